// Round 2
// baseline (14658.168 us; speedup 1.0000x reference)
//
#include <hip/hip_runtime.h>
#include <hip/hip_bf16.h>
#include <math.h>

typedef __bf16 bf16;
typedef bf16 bf16x8 __attribute__((ext_vector_type(8)));
typedef float f32x4 __attribute__((ext_vector_type(4)));

#define B_ 1024
#define T_ 64
#define D_ 1024
#define S_ 32
#define CH_ (B_*T_*S_)
#define DOFF_ ((size_t)6*CH_)
#define NBLK_ 512u

__device__ __forceinline__ float eluf(float x){ return x > 0.f ? x : expm1f(x); }
__device__ __forceinline__ float sigmoidf_(float x){ return 1.f/(1.f+expf(-x)); }
__device__ __forceinline__ float softplusf_(float x){
    return x > 0.f ? x + log1pf(expf(-x)) : log1pf(expf(x));
}

// async global->LDS, 16B per lane; LDS dest must be linear in lane order
__device__ __forceinline__ void gload16(const bf16* g, bf16* l){
    __builtin_amdgcn_global_load_lds(
        (const __attribute__((address_space(1))) void*)(g),
        (__attribute__((address_space(3))) void*)(l), 16, 0, 0);
}

// device-scope grid barrier: one 64B-padded counter per sync point.
// release-add to arrive, relaxed spin, acquire fence on exit.
__device__ __forceinline__ void gridbar(unsigned* __restrict__ bar, int id){
    __syncthreads();
    if (threadIdx.x == 0){
        unsigned* c = bar + (id << 4);          // 64B stride
        __hip_atomic_fetch_add(c, 1u, __ATOMIC_RELEASE, __HIP_MEMORY_SCOPE_AGENT);
        while (__hip_atomic_load(c, __ATOMIC_RELAXED, __HIP_MEMORY_SCOPE_AGENT) < NBLK_)
            __builtin_amdgcn_s_sleep(1);
        __builtin_amdgcn_fence(__ATOMIC_ACQUIRE, "agent");
    }
    __syncthreads();
}

// ---------------- fp32 -> bf16 conversion ----------------------------------
__global__ __launch_bounds__(256) void k_cvt(const float* __restrict__ src,
                                             bf16* __restrict__ dst, int n){
    int i = (blockIdx.x*256 + threadIdx.x)*4;
    if (i < n){
        float4 v = *reinterpret_cast<const float4*>(src + i);
        dst[i+0] = (bf16)v.x; dst[i+1] = (bf16)v.y;
        dst[i+2] = (bf16)v.z; dst[i+3] = (bf16)v.w;
    }
}

// ---------------- embeds fp32 [b][t][e] -> bf16 [t][b][e] ------------------
__global__ __launch_bounds__(256) void k_cvt_tr(const float* __restrict__ src,
                                                bf16* __restrict__ dst){
    int row = blockIdx.x;                 // flat b*T + t
    int b = row >> 6, t = row & 63;
    const float* s = src + (size_t)row*1024;
    bf16* d = dst + ((size_t)t*B_ + b)*1024;
    int i = threadIdx.x*4;
    float4 v = *reinterpret_cast<const float4*>(s + i);
    d[i+0] = (bf16)v.x; d[i+1] = (bf16)v.y;
    d[i+2] = (bf16)v.z; d[i+3] = (bf16)v.w;
}

// ---------------- h0 = elu([stoch0 | action_0] @ asp_W^T + asp_b) ----------
__global__ __launch_bounds__(256) void k_h0(const float* __restrict__ stoch0,
                                            const float* __restrict__ actions,
                                            const float* __restrict__ aspW,
                                            const float* __restrict__ aspb,
                                            bf16* __restrict__ h_buf){
    int m = blockIdx.x;
    __shared__ float av[64];
    int tid = threadIdx.x;
    if (tid < 32)      av[tid] = stoch0[m*S_ + tid];
    else if (tid < 64) av[tid] = actions[(size_t)m*T_*S_ + (tid-32)];
    __syncthreads();
    for (int c = 0; c < 4; c++){
        int n = c*256 + tid;
        float s = aspb[n];
        const float* wr = aspW + n*64;
        #pragma unroll 8
        for (int k = 0; k < 64; k++) s += av[k]*wr[k];
        h_buf[(size_t)m*D_ + n] = (bf16)eluf(s);
    }
}

// ---------------- embed GEMM: partial[t][b][n] (async-staged) --------------
__global__ __launch_bounds__(256) void k_pre(const bf16* __restrict__ embf,
                                             const bf16* __restrict__ poW1,
                                             bf16* __restrict__ part){
    int m0 = blockIdx.x * 64;
    int tid = threadIdx.x;
    int w = tid >> 6, l = tid & 63;
    int lr = l & 15, ko = l >> 4;
    __shared__ bf16 Bl[2][16*64*8];        // 16KB per buffer
    int arow = m0 + w*16 + lr;
    const bf16* Ab = embf + (size_t)arow*1024 + ko*8;
    for (int sub = 0; sub < 4; sub++){
        int c0 = sub*256;
        const bf16* sp[4];
        #pragma unroll
        for (int p = 0; p < 4; p++){
            int s = p*256 + tid;
            int f = s >> 6, sl = s & 63;
            int col = c0 + f*16 + (sl & 15);
            sp[p] = poW1 + (size_t)col*2048 + 1024 + (sl >> 4)*8;
        }
        // prologue: stage tile 0
        #pragma unroll
        for (int p = 0; p < 4; p++) gload16(sp[p], &Bl[0][(p*256 + tid)*8]);
        bf16x8 a = *(const bf16x8*)(Ab);
        __syncthreads();
        f32x4 acc[16] = {};
        for (int kt = 0; kt < 32; ++kt){
            int cur = kt & 1;
            if (kt < 31){
                int k1 = (kt+1)*32;
                #pragma unroll
                for (int p = 0; p < 4; p++)
                    gload16(sp[p] + k1, &Bl[cur ^ 1][(p*256 + tid)*8]);
            }
            bf16x8 an = a;
            if (kt < 31) an = *(const bf16x8*)(Ab + (kt+1)*32);
            const bf16* Br = &Bl[cur][0];
            #pragma unroll
            for (int f = 0; f < 16; f++){
                bf16x8 b = *(const bf16x8*)(&Br[((f*64) + l)*8]);
                acc[f] = __builtin_amdgcn_mfma_f32_16x16x32_bf16(a, b, acc[f], 0,0,0);
            }
            __syncthreads();
            a = an;
        }
        // epilogue: repack via LDS, full-line stores
        bf16* outT = &Bl[0][0];             // [64][256] overlay (32KB)
        #pragma unroll
        for (int f = 0; f < 16; f++){
            int col = f*16 + lr;
            #pragma unroll
            for (int r = 0; r < 4; r++)
                outT[(w*16 + ko*4 + r)*256 + col] = (bf16)acc[f][r];
        }
        __syncthreads();
        {
            int colb = (tid & 31)*8;
            int rbase = tid >> 5;
            #pragma unroll
            for (int j = 0; j < 8; j++){
                int row = rbase + j*8;
                *(uint4*)&part[(size_t)(m0 + row)*1024 + c0 + colb] =
                    *(const uint4*)&outT[row*256 + colb];
            }
        }
        __syncthreads();
    }
}

// ---------------- fused persistent step loop (manual grid barrier) ---------
// 512 blocks x 256 threads, 2 blocks/CU (launch_bounds-enforced). Per t:
// phase1 GRU (512 blk), bar, phase2 po1 (512 blk), bar, phase3 po_out
// (64 blk), bar.
struct SArgs {
    bf16* __restrict__ h_buf;
    bf16* __restrict__ dbuf0;
    bf16* __restrict__ dbuf1;
    const bf16* __restrict__ wih;
    const bf16* __restrict__ whh;
    const float* __restrict__ bih;
    const float* __restrict__ bhh;
    const float* __restrict__ deter0;
    float* __restrict__ dF0;
    float* __restrict__ dF1;
    float* __restrict__ out;
    const bf16* __restrict__ poW1;
    const float* __restrict__ pob1;
    bf16* __restrict__ partial;
    bf16* __restrict__ po1h;
    const bf16* __restrict__ poW2;
    const float* __restrict__ pob2;
    const float* __restrict__ noise_po;
    const float* __restrict__ actions;
    const bf16* __restrict__ aspW;
    const float* __restrict__ aspb;
    bf16* __restrict__ dall0;
    unsigned* __restrict__ bar;
};

__global__ __launch_bounds__(256, 2) void k_steps(SArgs a){
    __shared__ __align__(16) char smem[24576];   // max over phases (GRU: 2x12KB)
    int bid = blockIdx.x;
    int tid = threadIdx.x;
    int w = tid >> 6, l = tid & 63;
    int lr = l & 15, ko = l >> 4;

    // ---- t-invariant GRU/po1 geometry: 32 n-slices x 16 m-blocks ----
    int n = bid & 31, mb = bid >> 5;
    int j0 = n*32, m0g = mb*64;
    const bf16* spg[3];
    #pragma unroll
    for (int p = 0; p < 3; p++){
        int s = p*256 + tid;
        int f = s >> 6, sl = s & 63;
        int g = f >> 1, cfl = f & 1;
        int col = j0 + cfl*16 + (sl & 15);
        const bf16* base = (g < 3) ? a.wih : a.whh;
        int gg = (g < 3) ? g : g - 3;
        spg[p] = base + (size_t)(gg*1024 + col)*1024 + (sl >> 4)*8;
    }
    int arow = m0g + w*16 + lr;
    const bf16* hA = a.h_buf + (size_t)arow*1024 + ko*8;
    const bf16* spp;
    {   int f = tid >> 6, sl = tid & 63;
        int ksub = f >> 1, cfl = f & 1;
        int col = j0 + cfl*16 + (sl & 15);
        spp = a.poW1 + (size_t)col*2048 + ksub*32 + (sl >> 4)*8;
    }

    int sync_id = 0;
    for (int t = 0; t < T_; t++){
        // ================= phase 1: GRU =================
        {
            const float* dprev_f = (t == 0) ? a.deter0 : ((t & 1) ? a.dF1 : a.dF0);
            float* dcur_f = (((t+1) & 1)) ? a.dF1 : a.dF0;
            const bf16* dprev_bp = (t & 1) ? a.dbuf1 : a.dbuf0;
            bf16* dcur_bp = (((t+1) & 1)) ? a.dbuf1 : a.dbuf0;
            float* dout_t = a.out + DOFF_ + (size_t)t*D_;
            bf16* dall_t = (t == 0) ? a.dall0 : a.partial + (size_t)(t-1)*1048576;
            bf16 (*Bl)[6144] = (bf16(*)[6144])smem;
            const bf16* dA = dprev_bp + (size_t)arow*1024 + ko*8;
            #pragma unroll
            for (int p = 0; p < 3; p++) gload16(spg[p], &Bl[0][(p*256 + tid)*8]);
            bf16x8 aH = *(const bf16x8*)(hA);
            bf16x8 aD = *(const bf16x8*)(dA);
            __syncthreads();
            f32x4 acc[6][2] = {};
            for (int kt = 0; kt < 32; ++kt){
                int cur = kt & 1;
                if (kt < 31){
                    int k1 = (kt+1)*32;
                    #pragma unroll
                    for (int p = 0; p < 3; p++)
                        gload16(spg[p] + k1, &Bl[cur ^ 1][(p*256 + tid)*8]);
                }
                bf16x8 aHn = aH, aDn = aD;
                if (kt < 31){
                    aHn = *(const bf16x8*)(hA + (kt+1)*32);
                    aDn = *(const bf16x8*)(dA + (kt+1)*32);
                }
                const bf16* Br = &Bl[cur][0];
                #pragma unroll
                for (int g = 0; g < 6; g++){
                    #pragma unroll
                    for (int cfl = 0; cfl < 2; cfl++){
                        bf16x8 b = *(const bf16x8*)(&Br[((g*2 + cfl)*64 + l)*8]);
                        acc[g][cfl] = __builtin_amdgcn_mfma_f32_16x16x32_bf16(
                            g < 3 ? aH : aD, b, acc[g][cfl], 0,0,0);
                    }
                }
                __syncthreads();
                aH = aHn; aD = aDn;
            }
            #pragma unroll
            for (int cfl = 0; cfl < 2; cfl++){
                int j = j0 + cfl*16 + lr;
                float bir = a.bih[j],      bhr = a.bhh[j];
                float biz = a.bih[1024+j], bhz = a.bhh[1024+j];
                float bin = a.bih[2048+j], bhn = a.bhh[2048+j];
                #pragma unroll
                for (int r = 0; r < 4; r++){
                    int m = m0g + w*16 + ko*4 + r;
                    float ir  = acc[0][cfl][r] + bir;
                    float iz  = acc[1][cfl][r] + biz;
                    float in_ = acc[2][cfl][r] + bin;
                    float hr  = acc[3][cfl][r] + bhr;
                    float hz  = acc[4][cfl][r] + bhz;
                    float hn  = acc[5][cfl][r] + bhn;
                    float rg = sigmoidf_(ir + hr);
                    float zg = sigmoidf_(iz + hz);
                    float ng = tanhf(in_ + rg*hn);
                    float dp = dprev_f[(size_t)m*D_ + j];
                    float dn = (1.f - zg)*ng + zg*dp;
                    dout_t[(size_t)m*(T_*D_) + j] = dn;
                    dcur_f[(size_t)m*D_ + j] = dn;
                    bf16 dnb = (bf16)dn;
                    dcur_bp[(size_t)m*D_ + j] = dnb;
                    dall_t[(size_t)m*D_ + j] = dnb;
                }
            }
        }
        gridbar(a.bar, sync_id++);
        // ================= phase 2: po1 =================
        {
            const bf16* dcur_bp = (((t+1) & 1)) ? a.dbuf1 : a.dbuf0;
            bf16 (*Bl)[2048] = (bf16(*)[2048])smem;
            const bf16* A = dcur_bp + (size_t)arow*1024 + ko*8;
            gload16(spp, &Bl[0][tid*8]);
            bf16x8 a0 = *(const bf16x8*)(A);
            bf16x8 a1 = *(const bf16x8*)(A + 32);
            __syncthreads();
            f32x4 acc[2] = {};
            for (int kt = 0; kt < 16; ++kt){
                int cur = kt & 1;
                if (kt < 15) gload16(spp + (kt+1)*64, &Bl[cur ^ 1][tid*8]);
                bf16x8 a0n = a0, a1n = a1;
                if (kt < 15){
                    a0n = *(const bf16x8*)(A + (kt+1)*64);
                    a1n = *(const bf16x8*)(A + (kt+1)*64 + 32);
                }
                const bf16* Br = &Bl[cur][0];
                #pragma unroll
                for (int ksub = 0; ksub < 2; ksub++){
                    #pragma unroll
                    for (int cfl = 0; cfl < 2; cfl++){
                        bf16x8 b = *(const bf16x8*)(&Br[((ksub*2 + cfl)*64 + l)*8]);
                        acc[cfl] = __builtin_amdgcn_mfma_f32_16x16x32_bf16(
                            ksub ? a1 : a0, b, acc[cfl], 0,0,0);
                    }
                }
                __syncthreads();
                a0 = a0n; a1 = a1n;
            }
            #pragma unroll
            for (int cfl = 0; cfl < 2; cfl++){
                int col = j0 + cfl*16 + lr;
                float bb = a.pob1[col];
                #pragma unroll
                for (int r = 0; r < 4; r++){
                    int row = m0g + w*16 + ko*4 + r;
                    float v = acc[cfl][r] + bb +
                              (float)a.partial[((size_t)t*B_ + row)*1024 + col];
                    a.po1h[(size_t)row*1024 + col] = (bf16)eluf(v);
                }
            }
        }
        gridbar(a.bar, sync_id++);
        // ================= phase 3: po_out (64 blocks) =================
        if (bid < 64){
            int m0 = bid << 4;
            float (*ps)[16][68] = (float(*)[16][68])smem;           // 17408 B
            bf16 (*smA)[88] = (bf16(*)[88])(smem + 17408);          // 2816 B
            int ks = w * 256;
            f32x4 acc[4] = {};
            const bf16* apo = a.po1h + (size_t)(m0 + lr)*1024 + ks + ko*8;
            #pragma unroll
            for (int kk = 0; kk < 8; kk++){
                int k = kk*32;
                bf16x8 a2 = *(const bf16x8*)(apo + k);
                #pragma unroll
                for (int cf = 0; cf < 4; cf++){
                    bf16x8 b2 = *(const bf16x8*)(a.poW2 + (size_t)(cf*16+lr)*1024 + ks + k + ko*8);
                    acc[cf] = __builtin_amdgcn_mfma_f32_16x16x32_bf16(a2, b2, acc[cf], 0,0,0);
                }
            }
            #pragma unroll
            for (int cf = 0; cf < 4; cf++){
                int col = cf*16 + lr;
                #pragma unroll
                for (int r = 0; r < 4; r++) ps[w][ko*4+r][col] = acc[cf][r];
            }
            __syncthreads();
            for (int it = 0; it < 2; it++){
                int idx2 = tid + it*256;
                int s = idx2 & 31, mm = idx2 >> 5;
                int mg = m0 + mm;
                float qm  = ps[0][mm][s]    + ps[1][mm][s]    + ps[2][mm][s]    + ps[3][mm][s]    + a.pob2[s];
                float qls = ps[0][mm][32+s] + ps[1][mm][32+s] + ps[2][mm][32+s] + ps[3][mm][32+s] + a.pob2[32+s];
                float qstd = softplusf_(qls) + 0.1f;
                size_t no = (size_t)mg*(T_*S_) + (size_t)t*S_ + s;
                float qst = qm + a.noise_po[no]*qstd;
                a.out[0*(size_t)CH_ + no] = qm;
                a.out[1*(size_t)CH_ + no] = qstd;
                a.out[2*(size_t)CH_ + no] = qst;
                smA[mm][s] = (bf16)qst;
                if (t + 1 < T_)
                    smA[mm][32+s] = (bf16)a.actions[(size_t)mg*(T_*S_) + (size_t)(t+1)*S_ + s];
            }
            __syncthreads();
            if (t + 1 < T_){
                #pragma unroll 4
                for (int c2 = 0; c2 < 16; c2++){
                    int nb = w*256 + c2*16;
                    f32x4 a2v = {0.f, 0.f, 0.f, 0.f};
                    #pragma unroll
                    for (int kk = 0; kk < 2; kk++){
                        bf16x8 av = *(const bf16x8*)(&smA[lr][kk*32 + ko*8]);
                        bf16x8 bv = *(const bf16x8*)(a.aspW + (size_t)(nb+lr)*64 + kk*32 + ko*8);
                        a2v = __builtin_amdgcn_mfma_f32_16x16x32_bf16(av, bv, a2v, 0,0,0);
                    }
                    int n2 = nb + lr;
                    float bb = a.aspb[n2];
                    #pragma unroll
                    for (int r = 0; r < 4; r++)
                        a.h_buf[(size_t)(m0 + ko*4 + r)*1024 + n2] = (bf16)eluf(a2v[r] + bb);
                }
            }
        }
        gridbar(a.bar, sync_id++);
    }
}

// ---------------- batched prior path (async-staged B, padded rp1s) ---------
// 1024 blocks x 64 rows. rp1 (4 subtiles) -> rp1s -> rp2 -> sample.
__global__ __launch_bounds__(256) void k_prior(
        const bf16* __restrict__ dallP, const bf16* __restrict__ dall0,
        const bf16* __restrict__ rpW1, const float* __restrict__ rpb1,
        const bf16* __restrict__ rpW2, const float* __restrict__ rpb2,
        const float* __restrict__ noise_pr,
        float* __restrict__ out){
    int bid = blockIdx.x;
    int sl = bid >> 4;
    int b0 = (bid & 15)*64;
    int t  = (sl == 63) ? 0 : sl + 1;
    const bf16* Abase = (sl == 63) ? dall0 : dallP + (size_t)sl*1048576;
    int tid = threadIdx.x;
    int w = tid >> 6, l = tid & 63;
    int lr = l & 15, ko = l >> 4;
    __shared__ bf16 Bl[2][8192];       // 16KB per buffer
    __shared__ bf16 rp1s[64][264];     // padded (+8)
    const bf16* Ar = Abase + (size_t)(b0 + w*16 + lr)*1024 + ko*8;
    f32x4 acc2[4] = {};
    const bf16* sp[4];
    {   // sp for subtile 0
        #pragma unroll
        for (int p = 0; p < 4; p++){
            int s = p*256 + tid;
            int f = s >> 6, sl2 = s & 63;
            int col = f*16 + (sl2 & 15);
            sp[p] = rpW1 + (size_t)col*1024 + (sl2 >> 4)*8;
        }
    }
    // prologue: stage subtile-0 tile-0
    #pragma unroll
    for (int p = 0; p < 4; p++) gload16(sp[p], &Bl[0][(p*256 + tid)*8]);
    __syncthreads();
    for (int sub = 0; sub < 4; sub++){
        int c0 = sub*256;
        f32x4 acc[16] = {};
        bf16x8 a = *(const bf16x8*)(Ar);
        for (int kt = 0; kt < 32; ++kt){
            int cur = kt & 1;
            if (kt < 31){
                int k1 = (kt+1)*32;
                #pragma unroll
                for (int p = 0; p < 4; p++)
                    gload16(sp[p] + k1, &Bl[cur ^ 1][(p*256 + tid)*8]);
            }
            bf16x8 an = a;
            if (kt < 31) an = *(const bf16x8*)(Ar + (kt+1)*32);
            const bf16* Br = &Bl[cur][0];
            #pragma unroll
            for (int f = 0; f < 16; f++){
                bf16x8 b = *(const bf16x8*)(&Br[((f*64) + l)*8]);
                acc[f] = __builtin_amdgcn_mfma_f32_16x16x32_bf16(a, b, acc[f], 0,0,0);
            }
            __syncthreads();
            a = an;
        }
        // tail: issue next subtile's first tile into Bl[0] (hides under rp2)
        if (sub < 3){
            int c1 = c0 + 256;
            #pragma unroll
            for (int p = 0; p < 4; p++){
                int s = p*256 + tid;
                int f = s >> 6, sl2 = s & 63;
                int col = c1 + f*16 + (sl2 & 15);
                sp[p] = rpW1 + (size_t)col*1024 + (sl2 >> 4)*8;
                gload16(sp[p], &Bl[0][(p*256 + tid)*8]);
            }
        }
        // rp1 epilogue -> rp1s (padded)
        #pragma unroll
        for (int f = 0; f < 16; f++){
            int col = f*16 + lr;
            float bb = rpb1[c0 + col];
            #pragma unroll
            for (int r = 0; r < 4; r++)
                rp1s[w*16 + ko*4 + r][col] = (bf16)eluf(acc[f][r] + bb);
        }
        __syncthreads();
        // rp2 partial GEMM over this 256-col K-slice
        #pragma unroll
        for (int kk = 0; kk < 8; kk++){
            int k = kk*32;
            bf16x8 a2 = *(const bf16x8*)(&rp1s[w*16 + lr][k + ko*8]);
            #pragma unroll
            for (int cf = 0; cf < 4; cf++){
                bf16x8 b2 = *(const bf16x8*)(rpW2 + (size_t)(cf*16+lr)*1024 + c0 + k + ko*8);
                acc2[cf] = __builtin_amdgcn_mfma_f32_16x16x32_bf16(a2, b2, acc2[cf], 0,0,0);
            }
        }
        __syncthreads();   // rp1s reads done + Bl[0] stage drained (vmcnt at barrier)
    }
    #pragma unroll
    for (int cf = 0; cf < 2; cf++){
        int s = cf*16 + lr;
        float b1 = rpb2[s], b2 = rpb2[32+s];
        #pragma unroll
        for (int r = 0; r < 4; r++){
            int row = w*16 + ko*4 + r;
            float pm  = acc2[cf][r]   + b1;
            float pls = acc2[cf+2][r] + b2;
            float pstd = softplusf_(pls) + 0.1f;
            size_t no = (size_t)(b0 + row)*2048 + (size_t)t*32 + s;
            float pst = pm + noise_pr[no]*pstd;
            out[3*(size_t)CH_ + no] = pm;
            out[4*(size_t)CH_ + no] = pstd;
            out[5*(size_t)CH_ + no] = pst;
        }
    }
}

extern "C" void kernel_launch(void* const* d_in, const int* in_sizes, int n_in,
                              void* d_out, int out_size, void* d_ws, size_t ws_size,
                              hipStream_t stream) {
    const float* embeds   = (const float*)d_in[0];
    const float* actions  = (const float*)d_in[1];
    const float* deter0   = (const float*)d_in[2];
    const float* stoch0   = (const float*)d_in[3];
    const float* noise_pr = (const float*)d_in[4];
    const float* noise_po = (const float*)d_in[5];
    const float* asp_W    = (const float*)d_in[6];
    const float* asp_b    = (const float*)d_in[7];
    const float* w_ih     = (const float*)d_in[8];
    const float* w_hh     = (const float*)d_in[9];
    const float* b_ih     = (const float*)d_in[10];
    const float* b_hh     = (const float*)d_in[11];
    const float* rp_W1    = (const float*)d_in[12];
    const float* rp_b1    = (const float*)d_in[13];
    const float* rp_W2    = (const float*)d_in[14];
    const float* rp_b2    = (const float*)d_in[15];
    const float* po_W1    = (const float*)d_in[16];
    const float* po_b1    = (const float*)d_in[17];
    const float* po_W2    = (const float*)d_in[18];
    const float* po_b2    = (const float*)d_in[19];
    float* out = (float*)d_out;

    char* ws = (char*)d_ws;
    const size_t MB = 1024*1024;
    bf16*  h_buf   = (bf16*)(ws + 0*MB);
    bf16*  dbuf0   = (bf16*)(ws + 2*MB);
    bf16*  dbuf1   = (bf16*)(ws + 4*MB);
    bf16*  po1h    = (bf16*)(ws + 6*MB);
    float* dF0     = (float*)(ws + 10*MB);
    float* dF1     = (float*)(ws + 14*MB);
    bf16*  w_ih_b  = (bf16*)(ws + 18*MB);
    bf16*  w_hh_b  = (bf16*)(ws + 24*MB);
    bf16*  rpW1_b  = (bf16*)(ws + 30*MB);
    bf16*  poW1_b  = (bf16*)(ws + 32*MB);
    bf16*  rpW2_b  = (bf16*)(ws + 36*MB);
    bf16*  poW2_b  = (bf16*)(ws + 36*MB + 256*1024);
    bf16*  aspW_b  = (bf16*)(ws + 36*MB + 512*1024);
    unsigned* bar  = (unsigned*)(ws + 37*MB);              // 192 x 64B counters
    bf16*  dall0   = (bf16*)(ws + 38*MB);                  // 2MB: deter t=0 slab
    bf16*  partial = (bf16*)(ws + 40*MB);                  // 128MB, [t][b][n] slabs
    bf16*  embf    = (bf16*)(out + DOFF_);                 // scratch in d_out deter region

    hipMemsetAsync(bar, 0, 192*64, stream);

    auto cvt = [&](const float* s, bf16* d, int n){
        k_cvt<<<(n/4 + 255)/256, 256, 0, stream>>>(s, d, n);
    };
    cvt(w_ih,  w_ih_b, 3072*1024);
    cvt(w_hh,  w_hh_b, 3072*1024);
    cvt(rp_W1, rpW1_b, 1024*1024);
    cvt(po_W1, poW1_b, 1024*2048);
    cvt(rp_W2, rpW2_b, 64*1024);
    cvt(po_W2, poW2_b, 64*1024);
    cvt(asp_W, aspW_b, 1024*64);
    cvt(deter0, dbuf0, 1024*1024);
    k_h0<<<1024, 256, 0, stream>>>(stoch0, actions, asp_W, asp_b, h_buf);
    k_cvt_tr<<<B_*T_, 256, 0, stream>>>(embeds, embf);
    k_pre<<<1024, 256, 0, stream>>>(embf, poW1_b, partial);

    SArgs sa;
    sa.h_buf = h_buf;  sa.dbuf0 = dbuf0;  sa.dbuf1 = dbuf1;
    sa.wih = w_ih_b;   sa.whh = w_hh_b;
    sa.bih = b_ih;     sa.bhh = b_hh;
    sa.deter0 = deter0;
    sa.dF0 = dF0;      sa.dF1 = dF1;
    sa.out = out;
    sa.poW1 = poW1_b;  sa.pob1 = po_b1;
    sa.partial = partial;
    sa.po1h = po1h;
    sa.poW2 = poW2_b;  sa.pob2 = po_b2;
    sa.noise_po = noise_po;
    sa.actions = actions;
    sa.aspW = aspW_b;  sa.aspb = asp_b;
    sa.dall0 = dall0;
    sa.bar = bar;
    k_steps<<<512, 256, 0, stream>>>(sa);

    k_prior<<<1024, 256, 0, stream>>>(partial, dall0, rpW1_b, rp_b1,
                                      rpW2_b, rp_b2, noise_pr, out);
}

// Round 5
// 14373.050 us; speedup vs baseline: 1.0198x; 1.0198x over previous
//
#include <hip/hip_runtime.h>
#include <hip/hip_bf16.h>
#include <math.h>

typedef __bf16 bf16;
typedef bf16 bf16x8 __attribute__((ext_vector_type(8)));
typedef float f32x4 __attribute__((ext_vector_type(4)));
typedef unsigned long long u64;

#define B_ 1024
#define T_ 64
#define D_ 1024
#define S_ 32
#define CH_ (B_*T_*S_)
#define DOFF_ ((size_t)6*CH_)
#define NBLK_ 512u

__device__ __forceinline__ float eluf(float x){ return x > 0.f ? x : expm1f(x); }
__device__ __forceinline__ float sigmoidf_(float x){ return 1.f/(1.f+expf(-x)); }
__device__ __forceinline__ float softplusf_(float x){
    return x > 0.f ? x + log1pf(expf(-x)) : log1pf(expf(x));
}

// async global->LDS, 16B per lane; LDS dest must be linear in lane order
__device__ __forceinline__ void gload16(const bf16* g, bf16* l){
    __builtin_amdgcn_global_load_lds(
        (const __attribute__((address_space(1))) void*)(g),
        (__attribute__((address_space(3))) void*)(l), 16, 0, 0);
}

// ---- system-scope (LLC) accesses for cross-XCD handoff -------------------
// relaxed 8B atomic load/store -> global_load/store_dwordx2 sc0 sc1:
// bypass L1/L2, served by the die-level LLC.
__device__ __forceinline__ u64 ld_sys64(const void* p){
    return __hip_atomic_load((const u64*)p, __ATOMIC_RELAXED,
                             __HIP_MEMORY_SCOPE_SYSTEM);
}
__device__ __forceinline__ void st_sys64(void* p, u64 v){
    __hip_atomic_store((u64*)p, v, __ATOMIC_RELAXED,
                       __HIP_MEMORY_SCOPE_SYSTEM);
}
__device__ __forceinline__ bf16x8 ld_sys128(const bf16* p){
    union { u64 q[2]; bf16x8 v; } u;
    u.q[0] = ld_sys64(p);
    u.q[1] = ld_sys64(p + 4);
    return u.v;
}

// grid barrier: RELEASE on arrival (orders handoff stores before counter,
// no invalidate), relaxed spin, acquire-free exit (readers use LLC-bypass
// loads). Weights stay resident in L2/L1 across the whole loop.
__device__ __forceinline__ void gridbar(unsigned* __restrict__ bar, int id,
                                        bool rel){
    __syncthreads();
    if (threadIdx.x == 0){
        unsigned* c = bar + (id << 4);          // 64B stride
        if (rel)
            __hip_atomic_fetch_add(c, 1u, __ATOMIC_RELEASE,
                                   __HIP_MEMORY_SCOPE_AGENT);
        else
            __hip_atomic_fetch_add(c, 1u, __ATOMIC_RELAXED,
                                   __HIP_MEMORY_SCOPE_AGENT);
        while (__hip_atomic_load(c, __ATOMIC_RELAXED, __HIP_MEMORY_SCOPE_AGENT) < NBLK_)
            __builtin_amdgcn_s_sleep(4);
    }
    __syncthreads();
    asm volatile("" ::: "memory");
}

// ---------------- fp32 -> bf16 conversion ----------------------------------
__global__ __launch_bounds__(256) void k_cvt(const float* __restrict__ src,
                                             bf16* __restrict__ dst, int n){
    int i = (blockIdx.x*256 + threadIdx.x)*4;
    if (i < n){
        float4 v = *reinterpret_cast<const float4*>(src + i);
        dst[i+0] = (bf16)v.x; dst[i+1] = (bf16)v.y;
        dst[i+2] = (bf16)v.z; dst[i+3] = (bf16)v.w;
    }
}

// ---------------- embeds fp32 [b][t][e] -> bf16 [t][b][e] ------------------
__global__ __launch_bounds__(256) void k_cvt_tr(const float* __restrict__ src,
                                                bf16* __restrict__ dst){
    int row = blockIdx.x;                 // flat b*T + t
    int b = row >> 6, t = row & 63;
    const float* s = src + (size_t)row*1024;
    bf16* d = dst + ((size_t)t*B_ + b)*1024;
    int i = threadIdx.x*4;
    float4 v = *reinterpret_cast<const float4*>(s + i);
    d[i+0] = (bf16)v.x; d[i+1] = (bf16)v.y;
    d[i+2] = (bf16)v.z; d[i+3] = (bf16)v.w;
}

// ---------------- h0 = elu([stoch0 | action_0] @ asp_W^T + asp_b) ----------
__global__ __launch_bounds__(256) void k_h0(const float* __restrict__ stoch0,
                                            const float* __restrict__ actions,
                                            const float* __restrict__ aspW,
                                            const float* __restrict__ aspb,
                                            bf16* __restrict__ h_buf){
    int m = blockIdx.x;
    __shared__ float av[64];
    int tid = threadIdx.x;
    if (tid < 32)      av[tid] = stoch0[m*S_ + tid];
    else if (tid < 64) av[tid] = actions[(size_t)m*T_*S_ + (tid-32)];
    __syncthreads();
    for (int c = 0; c < 4; c++){
        int n = c*256 + tid;
        float s = aspb[n];
        const float* wr = aspW + n*64;
        #pragma unroll 8
        for (int k = 0; k < 64; k++) s += av[k]*wr[k];
        h_buf[(size_t)m*D_ + n] = (bf16)eluf(s);
    }
}

// ---------------- embed GEMM: partial[t][b][n] (async-staged) --------------
__global__ __launch_bounds__(256) void k_pre(const bf16* __restrict__ embf,
                                             const bf16* __restrict__ poW1,
                                             bf16* __restrict__ part){
    int m0 = blockIdx.x * 64;
    int tid = threadIdx.x;
    int w = tid >> 6, l = tid & 63;
    int lr = l & 15, ko = l >> 4;
    __shared__ bf16 Bl[2][16*64*8];        // 16KB per buffer
    int arow = m0 + w*16 + lr;
    const bf16* Ab = embf + (size_t)arow*1024 + ko*8;
    for (int sub = 0; sub < 4; sub++){
        int c0 = sub*256;
        const bf16* sp[4];
        #pragma unroll
        for (int p = 0; p < 4; p++){
            int s = p*256 + tid;
            int f = s >> 6, sl = s & 63;
            int col = c0 + f*16 + (sl & 15);
            sp[p] = poW1 + (size_t)col*2048 + 1024 + (sl >> 4)*8;
        }
        // prologue: stage tile 0
        #pragma unroll
        for (int p = 0; p < 4; p++) gload16(sp[p], &Bl[0][(p*256 + tid)*8]);
        bf16x8 a = *(const bf16x8*)(Ab);
        __syncthreads();
        f32x4 acc[16] = {};
        for (int kt = 0; kt < 32; ++kt){
            int cur = kt & 1;
            if (kt < 31){
                int k1 = (kt+1)*32;
                #pragma unroll
                for (int p = 0; p < 4; p++)
                    gload16(sp[p] + k1, &Bl[cur ^ 1][(p*256 + tid)*8]);
            }
            bf16x8 an = a;
            if (kt < 31) an = *(const bf16x8*)(Ab + (kt+1)*32);
            const bf16* Br = &Bl[cur][0];
            #pragma unroll
            for (int f = 0; f < 16; f++){
                bf16x8 b = *(const bf16x8*)(&Br[((f*64) + l)*8]);
                acc[f] = __builtin_amdgcn_mfma_f32_16x16x32_bf16(a, b, acc[f], 0,0,0);
            }
            __syncthreads();
            a = an;
        }
        // epilogue: repack via LDS, full-line stores
        bf16* outT = &Bl[0][0];             // [64][256] overlay (32KB)
        #pragma unroll
        for (int f = 0; f < 16; f++){
            int col = f*16 + lr;
            #pragma unroll
            for (int r = 0; r < 4; r++)
                outT[(w*16 + ko*4 + r)*256 + col] = (bf16)acc[f][r];
        }
        __syncthreads();
        {
            int colb = (tid & 31)*8;
            int rbase = tid >> 5;
            #pragma unroll
            for (int j = 0; j < 8; j++){
                int row = rbase + j*8;
                *(uint4*)&part[(size_t)(m0 + row)*1024 + c0 + colb] =
                    *(const uint4*)&outT[row*256 + colb];
            }
        }
        __syncthreads();
    }
}

// ---------------- fused persistent step loop -------------------------------
// 512 blocks x 256 threads, 2 blocks/CU. Handoff buffers (dbuf, po1h, h_buf)
// are touched ONLY via system-scope (sc0 sc1, LLC) ops inside this kernel;
// release-on-arrival orders them before the barrier counter. No acquire
// anywhere -> weights stay hot in L2/L1 across all 64 steps.
struct SArgs {
    bf16* __restrict__ h_buf;
    bf16* __restrict__ dbuf0;
    bf16* __restrict__ dbuf1;
    const bf16* __restrict__ wih;
    const bf16* __restrict__ whh;
    const float* __restrict__ bih;
    const float* __restrict__ bhh;
    const float* __restrict__ deter0;
    float* __restrict__ dF0;
    float* __restrict__ dF1;
    float* __restrict__ out;
    const bf16* __restrict__ poW1;
    const float* __restrict__ pob1;
    bf16* __restrict__ partial;
    bf16* __restrict__ po1h;
    const bf16* __restrict__ poW2;
    const float* __restrict__ pob2;
    const float* __restrict__ noise_po;
    const float* __restrict__ actions;
    const bf16* __restrict__ aspW;
    const float* __restrict__ aspb;
    bf16* __restrict__ dall0;
    unsigned* __restrict__ bar;
};

__global__ __launch_bounds__(256, 2) void k_steps(SArgs a){
    __shared__ __align__(16) char smem[24576];   // max over phases (GRU: 2x12KB)
    int bid = blockIdx.x;
    int tid = threadIdx.x;
    int w = tid >> 6, l = tid & 63;
    int lr = l & 15, ko = l >> 4;

    // ---- t-invariant GRU/po1 geometry: 32 n-slices x 16 m-blocks ----
    int n = bid & 31, mb = bid >> 5;
    int j0 = n*32, m0g = mb*64;
    const bf16* spg[3];
    #pragma unroll
    for (int p = 0; p < 3; p++){
        int s = p*256 + tid;
        int f = s >> 6, sl = s & 63;
        int g = f >> 1, cfl = f & 1;
        int col = j0 + cfl*16 + (sl & 15);
        const bf16* base = (g < 3) ? a.wih : a.whh;
        int gg = (g < 3) ? g : g - 3;
        spg[p] = base + (size_t)(gg*1024 + col)*1024 + (sl >> 4)*8;
    }
    int arow = m0g + w*16 + lr;
    const bf16* hA = a.h_buf + (size_t)arow*1024 + ko*8;
    const bf16* spp;
    {   int f = tid >> 6, sl = tid & 63;
        int ksub = f >> 1, cfl = f & 1;
        int col = j0 + cfl*16 + (sl & 15);
        spp = a.poW1 + (size_t)col*2048 + ksub*32 + (sl >> 4)*8;
    }

    int sync_id = 0;
    for (int t = 0; t < T_; t++){
        // ================= phase 1: GRU =================
        {
            const float* dprev_f = (t == 0) ? a.deter0 : ((t & 1) ? a.dF1 : a.dF0);
            float* dcur_f = (((t+1) & 1)) ? a.dF1 : a.dF0;
            const bf16* dprev_bp = (t & 1) ? a.dbuf1 : a.dbuf0;
            bf16* dcur_bp = (((t+1) & 1)) ? a.dbuf1 : a.dbuf0;
            float* dout_t = a.out + DOFF_ + (size_t)t*D_;
            bf16* dall_t = (t == 0) ? a.dall0 : a.partial + (size_t)(t-1)*1048576;
            bf16 (*Bl)[6144] = (bf16(*)[6144])smem;
            const bf16* dA = dprev_bp + (size_t)arow*1024 + ko*8;
            #pragma unroll
            for (int p = 0; p < 3; p++) gload16(spg[p], &Bl[0][(p*256 + tid)*8]);
            bf16x8 aH = ld_sys128(hA);
            bf16x8 aD = ld_sys128(dA);
            __syncthreads();
            f32x4 acc[6][2] = {};
            for (int kt = 0; kt < 32; ++kt){
                int cur = kt & 1;
                if (kt < 31){
                    int k1 = (kt+1)*32;
                    #pragma unroll
                    for (int p = 0; p < 3; p++)
                        gload16(spg[p] + k1, &Bl[cur ^ 1][(p*256 + tid)*8]);
                }
                bf16x8 aHn = aH, aDn = aD;
                if (kt < 31){
                    aHn = ld_sys128(hA + (kt+1)*32);
                    aDn = ld_sys128(dA + (kt+1)*32);
                }
                const bf16* Br = &Bl[cur][0];
                #pragma unroll
                for (int g = 0; g < 6; g++){
                    #pragma unroll
                    for (int cfl = 0; cfl < 2; cfl++){
                        bf16x8 b = *(const bf16x8*)(&Br[((g*2 + cfl)*64 + l)*8]);
                        acc[g][cfl] = __builtin_amdgcn_mfma_f32_16x16x32_bf16(
                            g < 3 ? aH : aD, b, acc[g][cfl], 0,0,0);
                    }
                }
                __syncthreads();
                aH = aHn; aD = aDn;
            }
            bf16 (*rp)[32] = (bf16(*)[32])smem;       // 4KB repack tile
            #pragma unroll
            for (int cfl = 0; cfl < 2; cfl++){
                int j = j0 + cfl*16 + lr;
                float bir = a.bih[j],      bhr = a.bhh[j];
                float biz = a.bih[1024+j], bhz = a.bhh[1024+j];
                float bin = a.bih[2048+j], bhn = a.bhh[2048+j];
                #pragma unroll
                for (int r = 0; r < 4; r++){
                    int m = m0g + w*16 + ko*4 + r;
                    float ir  = acc[0][cfl][r] + bir;
                    float iz  = acc[1][cfl][r] + biz;
                    float in_ = acc[2][cfl][r] + bin;
                    float hr  = acc[3][cfl][r] + bhr;
                    float hz  = acc[4][cfl][r] + bhz;
                    float hn  = acc[5][cfl][r] + bhn;
                    float rg = sigmoidf_(ir + hr);
                    float zg = sigmoidf_(iz + hz);
                    float ng = tanhf(in_ + rg*hn);
                    float dp = dprev_f[(size_t)m*D_ + j];
                    float dn = (1.f - zg)*ng + zg*dp;
                    dout_t[(size_t)m*(T_*D_) + j] = dn;
                    dcur_f[(size_t)m*D_ + j] = dn;
                    bf16 dnb = (bf16)dn;
                    dall_t[(size_t)m*D_ + j] = dnb;              // plain: read post-dispatch
                    rp[w*16 + ko*4 + r][cfl*16 + lr] = dnb;
                }
            }
            __syncthreads();
            {   // contiguous 16B/thread system stores of the [64][32] tile
                int row = tid >> 2, c8 = (tid & 3)*8;
                const u64* q = (const u64*)&rp[row][c8];
                bf16* gp = dcur_bp + (size_t)(m0g + row)*1024 + j0 + c8;
                st_sys64(gp,     q[0]);
                st_sys64(gp + 4, q[1]);
            }
        }
        gridbar(a.bar, sync_id++, true);
        // ================= phase 2: po1 =================
        {
            const bf16* dcur_bp = (((t+1) & 1)) ? a.dbuf1 : a.dbuf0;
            bf16 (*Bl)[2048] = (bf16(*)[2048])smem;
            const bf16* A = dcur_bp + (size_t)arow*1024 + ko*8;
            gload16(spp, &Bl[0][tid*8]);
            bf16x8 a0 = ld_sys128(A);
            bf16x8 a1 = ld_sys128(A + 32);
            __syncthreads();
            f32x4 acc[2] = {};
            for (int kt = 0; kt < 16; ++kt){
                int cur = kt & 1;
                if (kt < 15) gload16(spp + (kt+1)*64, &Bl[cur ^ 1][tid*8]);
                bf16x8 a0n = a0, a1n = a1;
                if (kt < 15){
                    a0n = ld_sys128(A + (kt+1)*64);
                    a1n = ld_sys128(A + (kt+1)*64 + 32);
                }
                const bf16* Br = &Bl[cur][0];
                #pragma unroll
                for (int ksub = 0; ksub < 2; ksub++){
                    #pragma unroll
                    for (int cfl = 0; cfl < 2; cfl++){
                        bf16x8 b = *(const bf16x8*)(&Br[((ksub*2 + cfl)*64 + l)*8]);
                        acc[cfl] = __builtin_amdgcn_mfma_f32_16x16x32_bf16(
                            ksub ? a1 : a0, b, acc[cfl], 0,0,0);
                    }
                }
                __syncthreads();
                a0 = a0n; a1 = a1n;
            }
            bf16 (*rp)[32] = (bf16(*)[32])smem;       // 4KB repack tile
            #pragma unroll
            for (int cfl = 0; cfl < 2; cfl++){
                int col = j0 + cfl*16 + lr;
                float bb = a.pob1[col];
                #pragma unroll
                for (int r = 0; r < 4; r++){
                    int row = m0g + w*16 + ko*4 + r;
                    float v = acc[cfl][r] + bb +
                              (float)a.partial[((size_t)t*B_ + row)*1024 + col];
                    rp[w*16 + ko*4 + r][cfl*16 + lr] = (bf16)eluf(v);
                }
            }
            __syncthreads();
            {
                int row = tid >> 2, c8 = (tid & 3)*8;
                const u64* q = (const u64*)&rp[row][c8];
                bf16* gp = a.po1h + (size_t)(m0g + row)*1024 + j0 + c8;
                st_sys64(gp,     q[0]);
                st_sys64(gp + 4, q[1]);
            }
        }
        gridbar(a.bar, sync_id++, true);
        // ================= phase 3: po_out (64 blocks) =================
        if (bid < 64){
            int m0 = bid << 4;
            float (*ps)[16][68] = (float(*)[16][68])smem;           // 17408 B
            bf16 (*smA)[88] = (bf16(*)[88])(smem + 17408);          // 2816 B
            // ping-pong cross-lane repack tile; barrier between write & read
            bf16 (*hrep)[2][16][16] = (bf16(*)[2][16][16])(smem + 20224); // 4096 B
            int ks = w * 256;
            f32x4 acc[4] = {};
            const bf16* apo = a.po1h + (size_t)(m0 + lr)*1024 + ks + ko*8;
            bf16x8 a2 = ld_sys128(apo);
            #pragma unroll
            for (int kk = 0; kk < 8; kk++){
                bf16x8 a2n = a2;
                if (kk < 7) a2n = ld_sys128(apo + (kk+1)*32);
                int k = kk*32;
                #pragma unroll
                for (int cf = 0; cf < 4; cf++){
                    bf16x8 b2 = *(const bf16x8*)(a.poW2 + (size_t)(cf*16+lr)*1024 + ks + k + ko*8);
                    acc[cf] = __builtin_amdgcn_mfma_f32_16x16x32_bf16(a2, b2, acc[cf], 0,0,0);
                }
                a2 = a2n;
            }
            #pragma unroll
            for (int cf = 0; cf < 4; cf++){
                int col = cf*16 + lr;
                #pragma unroll
                for (int r = 0; r < 4; r++) ps[w][ko*4+r][col] = acc[cf][r];
            }
            __syncthreads();
            for (int it = 0; it < 2; it++){
                int idx2 = tid + it*256;
                int s = idx2 & 31, mm = idx2 >> 5;
                int mg = m0 + mm;
                float qm  = ps[0][mm][s]    + ps[1][mm][s]    + ps[2][mm][s]    + ps[3][mm][s]    + a.pob2[s];
                float qls = ps[0][mm][32+s] + ps[1][mm][32+s] + ps[2][mm][32+s] + ps[3][mm][32+s] + a.pob2[32+s];
                float qstd = softplusf_(qls) + 0.1f;
                size_t no = (size_t)mg*(T_*S_) + (size_t)t*S_ + s;
                float qst = qm + a.noise_po[no]*qstd;
                a.out[0*(size_t)CH_ + no] = qm;
                a.out[1*(size_t)CH_ + no] = qstd;
                a.out[2*(size_t)CH_ + no] = qst;
                smA[mm][s] = (bf16)qst;
                if (t + 1 < T_)
                    smA[mm][32+s] = (bf16)a.actions[(size_t)mg*(T_*S_) + (size_t)(t+1)*S_ + s];
            }
            __syncthreads();
            if (t + 1 < T_){
                for (int c2 = 0; c2 < 16; c2++){
                    int nb = w*256 + c2*16;
                    int pb = c2 & 1;
                    f32x4 a2v = {0.f, 0.f, 0.f, 0.f};
                    #pragma unroll
                    for (int kk = 0; kk < 2; kk++){
                        bf16x8 av = *(const bf16x8*)(&smA[lr][kk*32 + ko*8]);
                        bf16x8 bv = *(const bf16x8*)(a.aspW + (size_t)(nb+lr)*64 + kk*32 + ko*8);
                        a2v = __builtin_amdgcn_mfma_f32_16x16x32_bf16(av, bv, a2v, 0,0,0);
                    }
                    int n2 = nb + lr;
                    float bb = a.aspb[n2];
                    #pragma unroll
                    for (int r = 0; r < 4; r++)
                        hrep[w][pb][ko*4 + r][lr] = (bf16)eluf(a2v[r] + bb);
                    __syncthreads();   // cross-lane LDS handoff needs a barrier
                    u64 q = *(const u64*)&hrep[w][pb][l >> 2][(l & 3)*4];
                    st_sys64(&a.h_buf[(size_t)(m0 + (l >> 2))*1024 + nb + (l & 3)*4], q);
                }
            }
        }
        gridbar(a.bar, sync_id++, bid < 64);
    }
}

// ---------------- batched prior path (async-staged B, padded rp1s) ---------
// 1024 blocks x 64 rows. rp1 (4 subtiles) -> rp1s -> rp2 -> sample.
__global__ __launch_bounds__(256) void k_prior(
        const bf16* __restrict__ dallP, const bf16* __restrict__ dall0,
        const bf16* __restrict__ rpW1, const float* __restrict__ rpb1,
        const bf16* __restrict__ rpW2, const float* __restrict__ rpb2,
        const float* __restrict__ noise_pr,
        float* __restrict__ out){
    int bid = blockIdx.x;
    int sl = bid >> 4;
    int b0 = (bid & 15)*64;
    int t  = (sl == 63) ? 0 : sl + 1;
    const bf16* Abase = (sl == 63) ? dall0 : dallP + (size_t)sl*1048576;
    int tid = threadIdx.x;
    int w = tid >> 6, l = tid & 63;
    int lr = l & 15, ko = l >> 4;
    __shared__ bf16 Bl[2][8192];       // 16KB per buffer
    __shared__ bf16 rp1s[64][264];     // padded (+8)
    const bf16* Ar = Abase + (size_t)(b0 + w*16 + lr)*1024 + ko*8;
    f32x4 acc2[4] = {};
    const bf16* sp[4];
    {   // sp for subtile 0
        #pragma unroll
        for (int p = 0; p < 4; p++){
            int s = p*256 + tid;
            int f = s >> 6, sl2 = s & 63;
            int col = f*16 + (sl2 & 15);
            sp[p] = rpW1 + (size_t)col*1024 + (sl2 >> 4)*8;
        }
    }
    // prologue: stage subtile-0 tile-0
    #pragma unroll
    for (int p = 0; p < 4; p++) gload16(sp[p], &Bl[0][(p*256 + tid)*8]);
    __syncthreads();
    for (int sub = 0; sub < 4; sub++){
        int c0 = sub*256;
        f32x4 acc[16] = {};
        bf16x8 a = *(const bf16x8*)(Ar);
        for (int kt = 0; kt < 32; ++kt){
            int cur = kt & 1;
            if (kt < 31){
                int k1 = (kt+1)*32;
                #pragma unroll
                for (int p = 0; p < 4; p++)
                    gload16(sp[p] + k1, &Bl[cur ^ 1][(p*256 + tid)*8]);
            }
            bf16x8 an = a;
            if (kt < 31) an = *(const bf16x8*)(Ar + (kt+1)*32);
            const bf16* Br = &Bl[cur][0];
            #pragma unroll
            for (int f = 0; f < 16; f++){
                bf16x8 b = *(const bf16x8*)(&Br[((f*64) + l)*8]);
                acc[f] = __builtin_amdgcn_mfma_f32_16x16x32_bf16(a, b, acc[f], 0,0,0);
            }
            __syncthreads();
            a = an;
        }
        // tail: issue next subtile's first tile into Bl[0] (hides under rp2)
        if (sub < 3){
            int c1 = c0 + 256;
            #pragma unroll
            for (int p = 0; p < 4; p++){
                int s = p*256 + tid;
                int f = s >> 6, sl2 = s & 63;
                int col = c1 + f*16 + (sl2 & 15);
                sp[p] = rpW1 + (size_t)col*1024 + (sl2 >> 4)*8;
                gload16(sp[p], &Bl[0][(p*256 + tid)*8]);
            }
        }
        // rp1 epilogue -> rp1s (padded)
        #pragma unroll
        for (int f = 0; f < 16; f++){
            int col = f*16 + lr;
            float bb = rpb1[c0 + col];
            #pragma unroll
            for (int r = 0; r < 4; r++)
                rp1s[w*16 + ko*4 + r][col] = (bf16)eluf(acc[f][r] + bb);
        }
        __syncthreads();
        // rp2 partial GEMM over this 256-col K-slice
        #pragma unroll
        for (int kk = 0; kk < 8; kk++){
            int k = kk*32;
            bf16x8 a2 = *(const bf16x8*)(&rp1s[w*16 + lr][k + ko*8]);
            #pragma unroll
            for (int cf = 0; cf < 4; cf++){
                bf16x8 b2 = *(const bf16x8*)(rpW2 + (size_t)(cf*16+lr)*1024 + c0 + k + ko*8);
                acc2[cf] = __builtin_amdgcn_mfma_f32_16x16x32_bf16(a2, b2, acc2[cf], 0,0,0);
            }
        }
        __syncthreads();   // rp1s reads done + Bl[0] stage drained (vmcnt at barrier)
    }
    #pragma unroll
    for (int cf = 0; cf < 2; cf++){
        int s = cf*16 + lr;
        float b1 = rpb2[s], b2 = rpb2[32+s];
        #pragma unroll
        for (int r = 0; r < 4; r++){
            int row = w*16 + ko*4 + r;
            float pm  = acc2[cf][r]   + b1;
            float pls = acc2[cf+2][r] + b2;
            float pstd = softplusf_(pls) + 0.1f;
            size_t no = (size_t)(b0 + row)*2048 + (size_t)t*32 + s;
            float pst = pm + noise_pr[no]*pstd;
            out[3*(size_t)CH_ + no] = pm;
            out[4*(size_t)CH_ + no] = pstd;
            out[5*(size_t)CH_ + no] = pst;
        }
    }
}

extern "C" void kernel_launch(void* const* d_in, const int* in_sizes, int n_in,
                              void* d_out, int out_size, void* d_ws, size_t ws_size,
                              hipStream_t stream) {
    const float* embeds   = (const float*)d_in[0];
    const float* actions  = (const float*)d_in[1];
    const float* deter0   = (const float*)d_in[2];
    const float* stoch0   = (const float*)d_in[3];
    const float* noise_pr = (const float*)d_in[4];
    const float* noise_po = (const float*)d_in[5];
    const float* asp_W    = (const float*)d_in[6];
    const float* asp_b    = (const float*)d_in[7];
    const float* w_ih     = (const float*)d_in[8];
    const float* w_hh     = (const float*)d_in[9];
    const float* b_ih     = (const float*)d_in[10];
    const float* b_hh     = (const float*)d_in[11];
    const float* rp_W1    = (const float*)d_in[12];
    const float* rp_b1    = (const float*)d_in[13];
    const float* rp_W2    = (const float*)d_in[14];
    const float* rp_b2    = (const float*)d_in[15];
    const float* po_W1    = (const float*)d_in[16];
    const float* po_b1    = (const float*)d_in[17];
    const float* po_W2    = (const float*)d_in[18];
    const float* po_b2    = (const float*)d_in[19];
    float* out = (float*)d_out;

    char* ws = (char*)d_ws;
    const size_t MB = 1024*1024;
    bf16*  h_buf   = (bf16*)(ws + 0*MB);
    bf16*  dbuf0   = (bf16*)(ws + 2*MB);
    bf16*  dbuf1   = (bf16*)(ws + 4*MB);
    bf16*  po1h    = (bf16*)(ws + 6*MB);
    float* dF0     = (float*)(ws + 10*MB);
    float* dF1     = (float*)(ws + 14*MB);
    bf16*  w_ih_b  = (bf16*)(ws + 18*MB);
    bf16*  w_hh_b  = (bf16*)(ws + 24*MB);
    bf16*  rpW1_b  = (bf16*)(ws + 30*MB);
    bf16*  poW1_b  = (bf16*)(ws + 32*MB);
    bf16*  rpW2_b  = (bf16*)(ws + 36*MB);
    bf16*  poW2_b  = (bf16*)(ws + 36*MB + 256*1024);
    bf16*  aspW_b  = (bf16*)(ws + 36*MB + 512*1024);
    unsigned* bar  = (unsigned*)(ws + 37*MB);              // 192 x 64B counters
    bf16*  dall0   = (bf16*)(ws + 38*MB);                  // 2MB: deter t=0 slab
    bf16*  partial = (bf16*)(ws + 40*MB);                  // 128MB, [t][b][n] slabs
    bf16*  embf    = (bf16*)(out + DOFF_);                 // scratch in d_out deter region

    hipMemsetAsync(bar, 0, 192*64, stream);

    auto cvt = [&](const float* s, bf16* d, int n){
        k_cvt<<<(n/4 + 255)/256, 256, 0, stream>>>(s, d, n);
    };
    cvt(w_ih,  w_ih_b, 3072*1024);
    cvt(w_hh,  w_hh_b, 3072*1024);
    cvt(rp_W1, rpW1_b, 1024*1024);
    cvt(po_W1, poW1_b, 1024*2048);
    cvt(rp_W2, rpW2_b, 64*1024);
    cvt(po_W2, poW2_b, 64*1024);
    cvt(asp_W, aspW_b, 1024*64);
    cvt(deter0, dbuf0, 1024*1024);
    k_h0<<<1024, 256, 0, stream>>>(stoch0, actions, asp_W, asp_b, h_buf);
    k_cvt_tr<<<B_*T_, 256, 0, stream>>>(embeds, embf);
    k_pre<<<1024, 256, 0, stream>>>(embf, poW1_b, partial);

    SArgs sa;
    sa.h_buf = h_buf;  sa.dbuf0 = dbuf0;  sa.dbuf1 = dbuf1;
    sa.wih = w_ih_b;   sa.whh = w_hh_b;
    sa.bih = b_ih;     sa.bhh = b_hh;
    sa.deter0 = deter0;
    sa.dF0 = dF0;      sa.dF1 = dF1;
    sa.out = out;
    sa.poW1 = poW1_b;  sa.pob1 = po_b1;
    sa.partial = partial;
    sa.po1h = po1h;
    sa.poW2 = poW2_b;  sa.pob2 = po_b2;
    sa.noise_po = noise_po;
    sa.actions = actions;
    sa.aspW = aspW_b;  sa.aspb = asp_b;
    sa.dall0 = dall0;
    sa.bar = bar;
    k_steps<<<512, 256, 0, stream>>>(sa);

    k_prior<<<1024, 256, 0, stream>>>(partial, dall0, rpW1_b, rp_b1,
                                      rpW2_b, rp_b2, noise_pr, out);
}

// Round 6
// 12189.020 us; speedup vs baseline: 1.2026x; 1.1792x over previous
//
#include <hip/hip_runtime.h>
#include <hip/hip_bf16.h>
#include <math.h>

typedef __bf16 bf16;
typedef bf16 bf16x8 __attribute__((ext_vector_type(8)));
typedef float f32x4 __attribute__((ext_vector_type(4)));
typedef unsigned long long u64;

#define B_ 1024
#define T_ 64
#define D_ 1024
#define S_ 32
#define CH_ (B_*T_*S_)
#define DOFF_ ((size_t)6*CH_)
#define NBLK_ 512u

__device__ __forceinline__ float eluf(float x){ return x > 0.f ? x : expm1f(x); }
__device__ __forceinline__ float sigmoidf_(float x){ return 1.f/(1.f+expf(-x)); }
__device__ __forceinline__ float softplusf_(float x){
    return x > 0.f ? x + log1pf(expf(-x)) : log1pf(expf(x));
}

// async global->LDS, 16B per lane; LDS dest must be linear in lane order
__device__ __forceinline__ void gload16(const bf16* g, bf16* l){
    __builtin_amdgcn_global_load_lds(
        (const __attribute__((address_space(1))) void*)(g),
        (__attribute__((address_space(3))) void*)(l), 16, 0, 0);
}

// ---- system-scope (LLC) accesses for cross-XCD handoff -------------------
// relaxed 8B atomic load/store -> global_load/store_dwordx2 sc0 sc1:
// bypass L1/L2, served by the die-level LLC.
__device__ __forceinline__ u64 ld_sys64(const void* p){
    return __hip_atomic_load((const u64*)p, __ATOMIC_RELAXED,
                             __HIP_MEMORY_SCOPE_SYSTEM);
}
__device__ __forceinline__ void st_sys64(void* p, u64 v){
    __hip_atomic_store((u64*)p, v, __ATOMIC_RELAXED,
                       __HIP_MEMORY_SCOPE_SYSTEM);
}
__device__ __forceinline__ bf16x8 ld_sys128(const bf16* p){
    union { u64 q[2]; bf16x8 v; } u;
    u.q[0] = ld_sys64(p);
    u.q[1] = ld_sys64(p + 4);
    return u.v;
}

// fully-relaxed grid barrier: NO release, NO acquire, NO cache walks.
// Ordering: handoff data moves via sc0|sc1 write-through stores; the
// __syncthreads before arrival drains vmcnt(0) (stores LLC-visible at
// retire -- validated by R3/R4 bit-identical-failure evidence); readers
// use LLC-bypass loads, so no invalidate is ever needed.
__device__ __forceinline__ void gridbar(unsigned* __restrict__ bar, int id){
    __syncthreads();
    if (threadIdx.x == 0){
        unsigned* c = bar + (id << 4);          // 64B stride
        __hip_atomic_fetch_add(c, 1u, __ATOMIC_RELAXED, __HIP_MEMORY_SCOPE_AGENT);
        while (__hip_atomic_load(c, __ATOMIC_RELAXED, __HIP_MEMORY_SCOPE_AGENT) < NBLK_)
            __builtin_amdgcn_s_sleep(4);
    }
    __syncthreads();
    asm volatile("" ::: "memory");
}

// ---------------- fp32 -> bf16 conversion ----------------------------------
__global__ __launch_bounds__(256) void k_cvt(const float* __restrict__ src,
                                             bf16* __restrict__ dst, int n){
    int i = (blockIdx.x*256 + threadIdx.x)*4;
    if (i < n){
        float4 v = *reinterpret_cast<const float4*>(src + i);
        dst[i+0] = (bf16)v.x; dst[i+1] = (bf16)v.y;
        dst[i+2] = (bf16)v.z; dst[i+3] = (bf16)v.w;
    }
}

// ---------------- embeds fp32 [b][t][e] -> bf16 [t][b][e] ------------------
__global__ __launch_bounds__(256) void k_cvt_tr(const float* __restrict__ src,
                                                bf16* __restrict__ dst){
    int row = blockIdx.x;                 // flat b*T + t
    int b = row >> 6, t = row & 63;
    const float* s = src + (size_t)row*1024;
    bf16* d = dst + ((size_t)t*B_ + b)*1024;
    int i = threadIdx.x*4;
    float4 v = *reinterpret_cast<const float4*>(s + i);
    d[i+0] = (bf16)v.x; d[i+1] = (bf16)v.y;
    d[i+2] = (bf16)v.z; d[i+3] = (bf16)v.w;
}

// ---------------- h0 = elu([stoch0 | action_0] @ asp_W^T + asp_b) ----------
__global__ __launch_bounds__(256) void k_h0(const float* __restrict__ stoch0,
                                            const float* __restrict__ actions,
                                            const float* __restrict__ aspW,
                                            const float* __restrict__ aspb,
                                            bf16* __restrict__ h_buf){
    int m = blockIdx.x;
    __shared__ float av[64];
    int tid = threadIdx.x;
    if (tid < 32)      av[tid] = stoch0[m*S_ + tid];
    else if (tid < 64) av[tid] = actions[(size_t)m*T_*S_ + (tid-32)];
    __syncthreads();
    for (int c = 0; c < 4; c++){
        int n = c*256 + tid;
        float s = aspb[n];
        const float* wr = aspW + n*64;
        #pragma unroll 8
        for (int k = 0; k < 64; k++) s += av[k]*wr[k];
        h_buf[(size_t)m*D_ + n] = (bf16)eluf(s);
    }
}

// ---------------- embed GEMM: partial[t][b][n] (async-staged) --------------
__global__ __launch_bounds__(256) void k_pre(const bf16* __restrict__ embf,
                                             const bf16* __restrict__ poW1,
                                             bf16* __restrict__ part){
    int m0 = blockIdx.x * 64;
    int tid = threadIdx.x;
    int w = tid >> 6, l = tid & 63;
    int lr = l & 15, ko = l >> 4;
    __shared__ bf16 Bl[2][16*64*8];        // 16KB per buffer
    int arow = m0 + w*16 + lr;
    const bf16* Ab = embf + (size_t)arow*1024 + ko*8;
    for (int sub = 0; sub < 4; sub++){
        int c0 = sub*256;
        const bf16* sp[4];
        #pragma unroll
        for (int p = 0; p < 4; p++){
            int s = p*256 + tid;
            int f = s >> 6, sl = s & 63;
            int col = c0 + f*16 + (sl & 15);
            sp[p] = poW1 + (size_t)col*2048 + 1024 + (sl >> 4)*8;
        }
        // prologue: stage tile 0
        #pragma unroll
        for (int p = 0; p < 4; p++) gload16(sp[p], &Bl[0][(p*256 + tid)*8]);
        bf16x8 a = *(const bf16x8*)(Ab);
        __syncthreads();
        f32x4 acc[16] = {};
        for (int kt = 0; kt < 32; ++kt){
            int cur = kt & 1;
            if (kt < 31){
                int k1 = (kt+1)*32;
                #pragma unroll
                for (int p = 0; p < 4; p++)
                    gload16(sp[p] + k1, &Bl[cur ^ 1][(p*256 + tid)*8]);
            }
            bf16x8 an = a;
            if (kt < 31) an = *(const bf16x8*)(Ab + (kt+1)*32);
            const bf16* Br = &Bl[cur][0];
            #pragma unroll
            for (int f = 0; f < 16; f++){
                bf16x8 b = *(const bf16x8*)(&Br[((f*64) + l)*8]);
                acc[f] = __builtin_amdgcn_mfma_f32_16x16x32_bf16(a, b, acc[f], 0,0,0);
            }
            __syncthreads();
            a = an;
        }
        // epilogue: repack via LDS, full-line stores
        bf16* outT = &Bl[0][0];             // [64][256] overlay (32KB)
        #pragma unroll
        for (int f = 0; f < 16; f++){
            int col = f*16 + lr;
            #pragma unroll
            for (int r = 0; r < 4; r++)
                outT[(w*16 + ko*4 + r)*256 + col] = (bf16)acc[f][r];
        }
        __syncthreads();
        {
            int colb = (tid & 31)*8;
            int rbase = tid >> 5;
            #pragma unroll
            for (int j = 0; j < 8; j++){
                int row = rbase + j*8;
                *(uint4*)&part[(size_t)(m0 + row)*1024 + c0 + colb] =
                    *(const uint4*)&outT[row*256 + colb];
            }
        }
        __syncthreads();
    }
}

// ---------------- fused persistent step loop -------------------------------
// 512 blocks x 256 threads, 2 blocks/CU. Handoff buffers (dbuf, po1h, h_buf)
// are touched ONLY via system-scope (sc0 sc1, LLC) ops inside this kernel.
// Plain stores (dout/dF/dall) need no coherence: dF is same-block across
// steps; dout/dall read only after kernel end.
struct SArgs {
    bf16* __restrict__ h_buf;
    bf16* __restrict__ dbuf0;
    bf16* __restrict__ dbuf1;
    const bf16* __restrict__ wih;
    const bf16* __restrict__ whh;
    const float* __restrict__ bih;
    const float* __restrict__ bhh;
    const float* __restrict__ deter0;
    float* __restrict__ dF0;
    float* __restrict__ dF1;
    float* __restrict__ out;
    const bf16* __restrict__ poW1;
    const float* __restrict__ pob1;
    bf16* __restrict__ partial;
    bf16* __restrict__ po1h;
    const bf16* __restrict__ poW2;
    const float* __restrict__ pob2;
    const float* __restrict__ noise_po;
    const float* __restrict__ actions;
    const bf16* __restrict__ aspW;
    const float* __restrict__ aspb;
    bf16* __restrict__ dall0;
    unsigned* __restrict__ bar;
};

__global__ __launch_bounds__(256, 2) void k_steps(SArgs a){
    __shared__ __align__(16) char smem[24576];   // max over phases (GRU: 2x12KB)
    int bid = blockIdx.x;
    int tid = threadIdx.x;
    int w = tid >> 6, l = tid & 63;
    int lr = l & 15, ko = l >> 4;

    // ---- t-invariant GRU/po1 geometry: 32 n-slices x 16 m-blocks ----
    int n = bid & 31, mb = bid >> 5;
    int j0 = n*32, m0g = mb*64;
    const bf16* spg[3];
    #pragma unroll
    for (int p = 0; p < 3; p++){
        int s = p*256 + tid;
        int f = s >> 6, sl = s & 63;
        int g = f >> 1, cfl = f & 1;
        int col = j0 + cfl*16 + (sl & 15);
        const bf16* base = (g < 3) ? a.wih : a.whh;
        int gg = (g < 3) ? g : g - 3;
        spg[p] = base + (size_t)(gg*1024 + col)*1024 + (sl >> 4)*8;
    }
    int arow = m0g + w*16 + lr;
    const bf16* hA = a.h_buf + (size_t)arow*1024 + ko*8;
    const bf16* spp;
    {   int f = tid >> 6, sl = tid & 63;
        int ksub = f >> 1, cfl = f & 1;
        int col = j0 + cfl*16 + (sl & 15);
        spp = a.poW1 + (size_t)col*2048 + ksub*32 + (sl >> 4)*8;
    }

    int sync_id = 0;
    for (int t = 0; t < T_; t++){
        // ================= phase 1: GRU =================
        {
            const float* dprev_f = (t == 0) ? a.deter0 : ((t & 1) ? a.dF1 : a.dF0);
            float* dcur_f = (((t+1) & 1)) ? a.dF1 : a.dF0;
            const bf16* dprev_bp = (t & 1) ? a.dbuf1 : a.dbuf0;
            bf16* dcur_bp = (((t+1) & 1)) ? a.dbuf1 : a.dbuf0;
            float* dout_t = a.out + DOFF_ + (size_t)t*D_;
            bf16* dall_t = (t == 0) ? a.dall0 : a.partial + (size_t)(t-1)*1048576;
            bf16 (*Bl)[6144] = (bf16(*)[6144])smem;
            const bf16* dA = dprev_bp + (size_t)arow*1024 + ko*8;
            #pragma unroll
            for (int p = 0; p < 3; p++) gload16(spg[p], &Bl[0][(p*256 + tid)*8]);
            bf16x8 aH = ld_sys128(hA);
            bf16x8 aD = ld_sys128(dA);
            __syncthreads();
            f32x4 acc[6][2] = {};
            for (int kt = 0; kt < 32; ++kt){
                int cur = kt & 1;
                if (kt < 31){
                    int k1 = (kt+1)*32;
                    #pragma unroll
                    for (int p = 0; p < 3; p++)
                        gload16(spg[p] + k1, &Bl[cur ^ 1][(p*256 + tid)*8]);
                }
                bf16x8 aHn = aH, aDn = aD;
                if (kt < 31){
                    aHn = ld_sys128(hA + (kt+1)*32);
                    aDn = ld_sys128(dA + (kt+1)*32);
                }
                const bf16* Br = &Bl[cur][0];
                #pragma unroll
                for (int g = 0; g < 6; g++){
                    #pragma unroll
                    for (int cfl = 0; cfl < 2; cfl++){
                        bf16x8 b = *(const bf16x8*)(&Br[((g*2 + cfl)*64 + l)*8]);
                        acc[g][cfl] = __builtin_amdgcn_mfma_f32_16x16x32_bf16(
                            g < 3 ? aH : aD, b, acc[g][cfl], 0,0,0);
                    }
                }
                __syncthreads();
                aH = aHn; aD = aDn;
            }
            bf16 (*rp)[32] = (bf16(*)[32])smem;       // 4KB repack tile
            #pragma unroll
            for (int cfl = 0; cfl < 2; cfl++){
                int j = j0 + cfl*16 + lr;
                float bir = a.bih[j],      bhr = a.bhh[j];
                float biz = a.bih[1024+j], bhz = a.bhh[1024+j];
                float bin = a.bih[2048+j], bhn = a.bhh[2048+j];
                #pragma unroll
                for (int r = 0; r < 4; r++){
                    int m = m0g + w*16 + ko*4 + r;
                    float ir  = acc[0][cfl][r] + bir;
                    float iz  = acc[1][cfl][r] + biz;
                    float in_ = acc[2][cfl][r] + bin;
                    float hr  = acc[3][cfl][r] + bhr;
                    float hz  = acc[4][cfl][r] + bhz;
                    float hn  = acc[5][cfl][r] + bhn;
                    float rg = sigmoidf_(ir + hr);
                    float zg = sigmoidf_(iz + hz);
                    float ng = tanhf(in_ + rg*hn);
                    float dp = dprev_f[(size_t)m*D_ + j];
                    float dn = (1.f - zg)*ng + zg*dp;
                    dout_t[(size_t)m*(T_*D_) + j] = dn;
                    dcur_f[(size_t)m*D_ + j] = dn;
                    bf16 dnb = (bf16)dn;
                    dall_t[(size_t)m*D_ + j] = dnb;              // plain: read post-dispatch
                    rp[w*16 + ko*4 + r][cfl*16 + lr] = dnb;
                }
            }
            __syncthreads();
            {   // contiguous 16B/thread system stores of the [64][32] tile
                int row = tid >> 2, c8 = (tid & 3)*8;
                const u64* q = (const u64*)&rp[row][c8];
                bf16* gp = dcur_bp + (size_t)(m0g + row)*1024 + j0 + c8;
                st_sys64(gp,     q[0]);
                st_sys64(gp + 4, q[1]);
            }
        }
        gridbar(a.bar, sync_id++);
        // ================= phase 2: po1 =================
        {
            const bf16* dcur_bp = (((t+1) & 1)) ? a.dbuf1 : a.dbuf0;
            bf16 (*Bl)[2048] = (bf16(*)[2048])smem;
            const bf16* A = dcur_bp + (size_t)arow*1024 + ko*8;
            gload16(spp, &Bl[0][tid*8]);
            bf16x8 a0 = ld_sys128(A);
            bf16x8 a1 = ld_sys128(A + 32);
            __syncthreads();
            f32x4 acc[2] = {};
            for (int kt = 0; kt < 16; ++kt){
                int cur = kt & 1;
                if (kt < 15) gload16(spp + (kt+1)*64, &Bl[cur ^ 1][tid*8]);
                bf16x8 a0n = a0, a1n = a1;
                if (kt < 15){
                    a0n = ld_sys128(A + (kt+1)*64);
                    a1n = ld_sys128(A + (kt+1)*64 + 32);
                }
                const bf16* Br = &Bl[cur][0];
                #pragma unroll
                for (int ksub = 0; ksub < 2; ksub++){
                    #pragma unroll
                    for (int cfl = 0; cfl < 2; cfl++){
                        bf16x8 b = *(const bf16x8*)(&Br[((ksub*2 + cfl)*64 + l)*8]);
                        acc[cfl] = __builtin_amdgcn_mfma_f32_16x16x32_bf16(
                            ksub ? a1 : a0, b, acc[cfl], 0,0,0);
                    }
                }
                __syncthreads();
                a0 = a0n; a1 = a1n;
            }
            bf16 (*rp)[32] = (bf16(*)[32])smem;       // 4KB repack tile
            #pragma unroll
            for (int cfl = 0; cfl < 2; cfl++){
                int col = j0 + cfl*16 + lr;
                float bb = a.pob1[col];
                #pragma unroll
                for (int r = 0; r < 4; r++){
                    int row = m0g + w*16 + ko*4 + r;
                    float v = acc[cfl][r] + bb +
                              (float)a.partial[((size_t)t*B_ + row)*1024 + col];
                    rp[w*16 + ko*4 + r][cfl*16 + lr] = (bf16)eluf(v);
                }
            }
            __syncthreads();
            {
                int row = tid >> 2, c8 = (tid & 3)*8;
                const u64* q = (const u64*)&rp[row][c8];
                bf16* gp = a.po1h + (size_t)(m0g + row)*1024 + j0 + c8;
                st_sys64(gp,     q[0]);
                st_sys64(gp + 4, q[1]);
            }
        }
        gridbar(a.bar, sync_id++);
        // ================= phase 3: po_out (64 blocks) =================
        if (bid < 64){
            int m0 = bid << 4;
            float (*ps)[16][68] = (float(*)[16][68])smem;           // 17408 B
            bf16 (*smA)[88] = (bf16(*)[88])(smem + 17408);          // 2816 B
            // ping-pong cross-lane repack tile; barrier between write & read
            bf16 (*hrep)[2][16][16] = (bf16(*)[2][16][16])(smem + 20224); // 4096 B
            int ks = w * 256;
            f32x4 acc[4] = {};
            const bf16* apo = a.po1h + (size_t)(m0 + lr)*1024 + ks + ko*8;
            bf16x8 a2 = ld_sys128(apo);
            #pragma unroll
            for (int kk = 0; kk < 8; kk++){
                bf16x8 a2n = a2;
                if (kk < 7) a2n = ld_sys128(apo + (kk+1)*32);
                int k = kk*32;
                #pragma unroll
                for (int cf = 0; cf < 4; cf++){
                    bf16x8 b2 = *(const bf16x8*)(a.poW2 + (size_t)(cf*16+lr)*1024 + ks + k + ko*8);
                    acc[cf] = __builtin_amdgcn_mfma_f32_16x16x32_bf16(a2, b2, acc[cf], 0,0,0);
                }
                a2 = a2n;
            }
            #pragma unroll
            for (int cf = 0; cf < 4; cf++){
                int col = cf*16 + lr;
                #pragma unroll
                for (int r = 0; r < 4; r++) ps[w][ko*4+r][col] = acc[cf][r];
            }
            __syncthreads();
            for (int it = 0; it < 2; it++){
                int idx2 = tid + it*256;
                int s = idx2 & 31, mm = idx2 >> 5;
                int mg = m0 + mm;
                float qm  = ps[0][mm][s]    + ps[1][mm][s]    + ps[2][mm][s]    + ps[3][mm][s]    + a.pob2[s];
                float qls = ps[0][mm][32+s] + ps[1][mm][32+s] + ps[2][mm][32+s] + ps[3][mm][32+s] + a.pob2[32+s];
                float qstd = softplusf_(qls) + 0.1f;
                size_t no = (size_t)mg*(T_*S_) + (size_t)t*S_ + s;
                float qst = qm + a.noise_po[no]*qstd;
                a.out[0*(size_t)CH_ + no] = qm;
                a.out[1*(size_t)CH_ + no] = qstd;
                a.out[2*(size_t)CH_ + no] = qst;
                smA[mm][s] = (bf16)qst;
                if (t + 1 < T_)
                    smA[mm][32+s] = (bf16)a.actions[(size_t)mg*(T_*S_) + (size_t)(t+1)*S_ + s];
            }
            __syncthreads();
            if (t + 1 < T_){
                for (int c2 = 0; c2 < 16; c2++){
                    int nb = w*256 + c2*16;
                    int pb = c2 & 1;
                    f32x4 a2v = {0.f, 0.f, 0.f, 0.f};
                    #pragma unroll
                    for (int kk = 0; kk < 2; kk++){
                        bf16x8 av = *(const bf16x8*)(&smA[lr][kk*32 + ko*8]);
                        bf16x8 bv = *(const bf16x8*)(a.aspW + (size_t)(nb+lr)*64 + kk*32 + ko*8);
                        a2v = __builtin_amdgcn_mfma_f32_16x16x32_bf16(av, bv, a2v, 0,0,0);
                    }
                    int n2 = nb + lr;
                    float bb = a.aspb[n2];
                    #pragma unroll
                    for (int r = 0; r < 4; r++)
                        hrep[w][pb][ko*4 + r][lr] = (bf16)eluf(a2v[r] + bb);
                    __syncthreads();   // cross-lane LDS handoff needs a barrier
                    u64 q = *(const u64*)&hrep[w][pb][l >> 2][(l & 3)*4];
                    st_sys64(&a.h_buf[(size_t)(m0 + (l >> 2))*1024 + nb + (l & 3)*4], q);
                }
            }
        }
        gridbar(a.bar, sync_id++);
    }
}

// ---------------- batched prior path (async-staged B, padded rp1s) ---------
// 1024 blocks x 64 rows. rp1 (4 subtiles) -> rp1s -> rp2 -> sample.
__global__ __launch_bounds__(256) void k_prior(
        const bf16* __restrict__ dallP, const bf16* __restrict__ dall0,
        const bf16* __restrict__ rpW1, const float* __restrict__ rpb1,
        const bf16* __restrict__ rpW2, const float* __restrict__ rpb2,
        const float* __restrict__ noise_pr,
        float* __restrict__ out){
    int bid = blockIdx.x;
    int sl = bid >> 4;
    int b0 = (bid & 15)*64;
    int t  = (sl == 63) ? 0 : sl + 1;
    const bf16* Abase = (sl == 63) ? dall0 : dallP + (size_t)sl*1048576;
    int tid = threadIdx.x;
    int w = tid >> 6, l = tid & 63;
    int lr = l & 15, ko = l >> 4;
    __shared__ bf16 Bl[2][8192];       // 16KB per buffer
    __shared__ bf16 rp1s[64][264];     // padded (+8)
    const bf16* Ar = Abase + (size_t)(b0 + w*16 + lr)*1024 + ko*8;
    f32x4 acc2[4] = {};
    const bf16* sp[4];
    {   // sp for subtile 0
        #pragma unroll
        for (int p = 0; p < 4; p++){
            int s = p*256 + tid;
            int f = s >> 6, sl2 = s & 63;
            int col = f*16 + (sl2 & 15);
            sp[p] = rpW1 + (size_t)col*1024 + (sl2 >> 4)*8;
        }
    }
    // prologue: stage subtile-0 tile-0
    #pragma unroll
    for (int p = 0; p < 4; p++) gload16(sp[p], &Bl[0][(p*256 + tid)*8]);
    __syncthreads();
    for (int sub = 0; sub < 4; sub++){
        int c0 = sub*256;
        f32x4 acc[16] = {};
        bf16x8 a = *(const bf16x8*)(Ar);
        for (int kt = 0; kt < 32; ++kt){
            int cur = kt & 1;
            if (kt < 31){
                int k1 = (kt+1)*32;
                #pragma unroll
                for (int p = 0; p < 4; p++)
                    gload16(sp[p] + k1, &Bl[cur ^ 1][(p*256 + tid)*8]);
            }
            bf16x8 an = a;
            if (kt < 31) an = *(const bf16x8*)(Ar + (kt+1)*32);
            const bf16* Br = &Bl[cur][0];
            #pragma unroll
            for (int f = 0; f < 16; f++){
                bf16x8 b = *(const bf16x8*)(&Br[((f*64) + l)*8]);
                acc[f] = __builtin_amdgcn_mfma_f32_16x16x32_bf16(a, b, acc[f], 0,0,0);
            }
            __syncthreads();
            a = an;
        }
        // tail: issue next subtile's first tile into Bl[0] (hides under rp2)
        if (sub < 3){
            int c1 = c0 + 256;
            #pragma unroll
            for (int p = 0; p < 4; p++){
                int s = p*256 + tid;
                int f = s >> 6, sl2 = s & 63;
                int col = c1 + f*16 + (sl2 & 15);
                sp[p] = rpW1 + (size_t)col*1024 + (sl2 >> 4)*8;
                gload16(sp[p], &Bl[0][(p*256 + tid)*8]);
            }
        }
        // rp1 epilogue -> rp1s (padded)
        #pragma unroll
        for (int f = 0; f < 16; f++){
            int col = f*16 + lr;
            float bb = rpb1[c0 + col];
            #pragma unroll
            for (int r = 0; r < 4; r++)
                rp1s[w*16 + ko*4 + r][col] = (bf16)eluf(acc[f][r] + bb);
        }
        __syncthreads();
        // rp2 partial GEMM over this 256-col K-slice
        #pragma unroll
        for (int kk = 0; kk < 8; kk++){
            int k = kk*32;
            bf16x8 a2 = *(const bf16x8*)(&rp1s[w*16 + lr][k + ko*8]);
            #pragma unroll
            for (int cf = 0; cf < 4; cf++){
                bf16x8 b2 = *(const bf16x8*)(rpW2 + (size_t)(cf*16+lr)*1024 + c0 + k + ko*8);
                acc2[cf] = __builtin_amdgcn_mfma_f32_16x16x32_bf16(a2, b2, acc2[cf], 0,0,0);
            }
        }
        __syncthreads();   // rp1s reads done + Bl[0] stage drained (vmcnt at barrier)
    }
    #pragma unroll
    for (int cf = 0; cf < 2; cf++){
        int s = cf*16 + lr;
        float b1 = rpb2[s], b2 = rpb2[32+s];
        #pragma unroll
        for (int r = 0; r < 4; r++){
            int row = w*16 + ko*4 + r;
            float pm  = acc2[cf][r]   + b1;
            float pls = acc2[cf+2][r] + b2;
            float pstd = softplusf_(pls) + 0.1f;
            size_t no = (size_t)(b0 + row)*2048 + (size_t)t*32 + s;
            float pst = pm + noise_pr[no]*pstd;
            out[3*(size_t)CH_ + no] = pm;
            out[4*(size_t)CH_ + no] = pstd;
            out[5*(size_t)CH_ + no] = pst;
        }
    }
}

extern "C" void kernel_launch(void* const* d_in, const int* in_sizes, int n_in,
                              void* d_out, int out_size, void* d_ws, size_t ws_size,
                              hipStream_t stream) {
    const float* embeds   = (const float*)d_in[0];
    const float* actions  = (const float*)d_in[1];
    const float* deter0   = (const float*)d_in[2];
    const float* stoch0   = (const float*)d_in[3];
    const float* noise_pr = (const float*)d_in[4];
    const float* noise_po = (const float*)d_in[5];
    const float* asp_W    = (const float*)d_in[6];
    const float* asp_b    = (const float*)d_in[7];
    const float* w_ih     = (const float*)d_in[8];
    const float* w_hh     = (const float*)d_in[9];
    const float* b_ih     = (const float*)d_in[10];
    const float* b_hh     = (const float*)d_in[11];
    const float* rp_W1    = (const float*)d_in[12];
    const float* rp_b1    = (const float*)d_in[13];
    const float* rp_W2    = (const float*)d_in[14];
    const float* rp_b2    = (const float*)d_in[15];
    const float* po_W1    = (const float*)d_in[16];
    const float* po_b1    = (const float*)d_in[17];
    const float* po_W2    = (const float*)d_in[18];
    const float* po_b2    = (const float*)d_in[19];
    float* out = (float*)d_out;

    char* ws = (char*)d_ws;
    const size_t MB = 1024*1024;
    bf16*  h_buf   = (bf16*)(ws + 0*MB);
    bf16*  dbuf0   = (bf16*)(ws + 2*MB);
    bf16*  dbuf1   = (bf16*)(ws + 4*MB);
    bf16*  po1h    = (bf16*)(ws + 6*MB);
    float* dF0     = (float*)(ws + 10*MB);
    float* dF1     = (float*)(ws + 14*MB);
    bf16*  w_ih_b  = (bf16*)(ws + 18*MB);
    bf16*  w_hh_b  = (bf16*)(ws + 24*MB);
    bf16*  rpW1_b  = (bf16*)(ws + 30*MB);
    bf16*  poW1_b  = (bf16*)(ws + 32*MB);
    bf16*  rpW2_b  = (bf16*)(ws + 36*MB);
    bf16*  poW2_b  = (bf16*)(ws + 36*MB + 256*1024);
    bf16*  aspW_b  = (bf16*)(ws + 36*MB + 512*1024);
    unsigned* bar  = (unsigned*)(ws + 37*MB);              // 192 x 64B counters
    bf16*  dall0   = (bf16*)(ws + 38*MB);                  // 2MB: deter t=0 slab
    bf16*  partial = (bf16*)(ws + 40*MB);                  // 128MB, [t][b][n] slabs
    bf16*  embf    = (bf16*)(out + DOFF_);                 // scratch in d_out deter region

    hipMemsetAsync(bar, 0, 192*64, stream);

    auto cvt = [&](const float* s, bf16* d, int n){
        k_cvt<<<(n/4 + 255)/256, 256, 0, stream>>>(s, d, n);
    };
    cvt(w_ih,  w_ih_b, 3072*1024);
    cvt(w_hh,  w_hh_b, 3072*1024);
    cvt(rp_W1, rpW1_b, 1024*1024);
    cvt(po_W1, poW1_b, 1024*2048);
    cvt(rp_W2, rpW2_b, 64*1024);
    cvt(po_W2, poW2_b, 64*1024);
    cvt(asp_W, aspW_b, 1024*64);
    cvt(deter0, dbuf0, 1024*1024);
    k_h0<<<1024, 256, 0, stream>>>(stoch0, actions, asp_W, asp_b, h_buf);
    k_cvt_tr<<<B_*T_, 256, 0, stream>>>(embeds, embf);
    k_pre<<<1024, 256, 0, stream>>>(embf, poW1_b, partial);

    SArgs sa;
    sa.h_buf = h_buf;  sa.dbuf0 = dbuf0;  sa.dbuf1 = dbuf1;
    sa.wih = w_ih_b;   sa.whh = w_hh_b;
    sa.bih = b_ih;     sa.bhh = b_hh;
    sa.deter0 = deter0;
    sa.dF0 = dF0;      sa.dF1 = dF1;
    sa.out = out;
    sa.poW1 = poW1_b;  sa.pob1 = po_b1;
    sa.partial = partial;
    sa.po1h = po1h;
    sa.poW2 = poW2_b;  sa.pob2 = po_b2;
    sa.noise_po = noise_po;
    sa.actions = actions;
    sa.aspW = aspW_b;  sa.aspb = asp_b;
    sa.dall0 = dall0;
    sa.bar = bar;
    k_steps<<<512, 256, 0, stream>>>(sa);

    k_prior<<<1024, 256, 0, stream>>>(partial, dall0, rpW1_b, rp_b1,
                                      rpW2_b, rp_b2, noise_pr, out);
}

// Round 7
// 11169.382 us; speedup vs baseline: 1.3124x; 1.0913x over previous
//
#include <hip/hip_runtime.h>
#include <hip/hip_bf16.h>
#include <math.h>

typedef __bf16 bf16;
typedef bf16 bf16x8 __attribute__((ext_vector_type(8)));
typedef float f32x4 __attribute__((ext_vector_type(4)));
typedef unsigned long long u64;

#define B_ 1024
#define T_ 64
#define D_ 1024
#define S_ 32
#define CH_ (B_*T_*S_)
#define DOFF_ ((size_t)6*CH_)
#define NBLK_ 512u
#define SLAB_ ((size_t)1048576)   // bf16 elems per t-slab (2MB)

__device__ __forceinline__ float eluf(float x){ return x > 0.f ? x : expm1f(x); }
__device__ __forceinline__ float sigmoidf_(float x){ return 1.f/(1.f+expf(-x)); }
__device__ __forceinline__ float softplusf_(float x){
    return x > 0.f ? x + log1pf(expf(-x)) : log1pf(expf(x));
}

// async global->LDS, 16B per lane; LDS dest must be linear in lane order
__device__ __forceinline__ void gload16(const bf16* g, bf16* l){
    __builtin_amdgcn_global_load_lds(
        (const __attribute__((address_space(1))) void*)(g),
        (__attribute__((address_space(3))) void*)(l), 16, 0, 0);
}

// ---- system-scope (LLC) accesses: write-through stores for handoff, ------
// uncached loads only where cached would be stale-prone (embed slabs, po1h).
__device__ __forceinline__ u64 ld_sys64(const void* p){
    return __hip_atomic_load((const u64*)p, __ATOMIC_RELAXED,
                             __HIP_MEMORY_SCOPE_SYSTEM);
}
__device__ __forceinline__ void st_sys64(void* p, u64 v){
    __hip_atomic_store((u64*)p, v, __ATOMIC_RELAXED,
                       __HIP_MEMORY_SCOPE_SYSTEM);
}
__device__ __forceinline__ bf16x8 ld_sys128(const bf16* p){
    union { u64 q[2]; bf16x8 v; } u;
    u.q[0] = ld_sys64(p);
    u.q[1] = ld_sys64(p + 4);
    return u.v;
}

// fully-relaxed grid barrier (R6-proven): __syncthreads drains vmcnt(0)
// (write-through stores LLC-visible at retire), readers never cache stale
// lines (fresh t-indexed slabs / sysloads), so no fences or cache walks.
__device__ __forceinline__ void gridbar(unsigned* __restrict__ bar, int id){
    __syncthreads();
    if (threadIdx.x == 0){
        unsigned* c = bar + (id << 4);          // 64B stride
        __hip_atomic_fetch_add(c, 1u, __ATOMIC_RELAXED, __HIP_MEMORY_SCOPE_AGENT);
        while (__hip_atomic_load(c, __ATOMIC_RELAXED, __HIP_MEMORY_SCOPE_AGENT) < NBLK_)
            __builtin_amdgcn_s_sleep(4);
    }
    __syncthreads();
    asm volatile("" ::: "memory");
}

// ---------------- fp32 -> bf16 conversion ----------------------------------
__global__ __launch_bounds__(256) void k_cvt(const float* __restrict__ src,
                                             bf16* __restrict__ dst, int n){
    int i = (blockIdx.x*256 + threadIdx.x)*4;
    if (i < n){
        float4 v = *reinterpret_cast<const float4*>(src + i);
        dst[i+0] = (bf16)v.x; dst[i+1] = (bf16)v.y;
        dst[i+2] = (bf16)v.z; dst[i+3] = (bf16)v.w;
    }
}

// ---------------- embeds fp32 [b][t][e] -> bf16 [t][b][e] ------------------
__global__ __launch_bounds__(256) void k_cvt_tr(const float* __restrict__ src,
                                                bf16* __restrict__ dst){
    int row = blockIdx.x;                 // flat b*T + t
    int b = row >> 6, t = row & 63;
    const float* s = src + (size_t)row*1024;
    bf16* d = dst + ((size_t)t*B_ + b)*1024;
    int i = threadIdx.x*4;
    float4 v = *reinterpret_cast<const float4*>(s + i);
    d[i+0] = (bf16)v.x; d[i+1] = (bf16)v.y;
    d[i+2] = (bf16)v.z; d[i+3] = (bf16)v.w;
}

// ---------------- h0 = elu([stoch0 | action_0] @ asp_W^T + asp_b) ----------
__global__ __launch_bounds__(256) void k_h0(const float* __restrict__ stoch0,
                                            const float* __restrict__ actions,
                                            const float* __restrict__ aspW,
                                            const float* __restrict__ aspb,
                                            bf16* __restrict__ h_dst){
    int m = blockIdx.x;
    __shared__ float av[64];
    int tid = threadIdx.x;
    if (tid < 32)      av[tid] = stoch0[m*S_ + tid];
    else if (tid < 64) av[tid] = actions[(size_t)m*T_*S_ + (tid-32)];
    __syncthreads();
    for (int c = 0; c < 4; c++){
        int n = c*256 + tid;
        float s = aspb[n];
        const float* wr = aspW + n*64;
        #pragma unroll 8
        for (int k = 0; k < 64; k++) s += av[k]*wr[k];
        h_dst[(size_t)m*D_ + n] = (bf16)eluf(s);
    }
}

// ---------------- embed GEMM: partial[t][b][n] (async-staged) --------------
__global__ __launch_bounds__(256) void k_pre(const bf16* __restrict__ embf,
                                             const bf16* __restrict__ poW1,
                                             bf16* __restrict__ part){
    int m0 = blockIdx.x * 64;
    int tid = threadIdx.x;
    int w = tid >> 6, l = tid & 63;
    int lr = l & 15, ko = l >> 4;
    __shared__ bf16 Bl[2][16*64*8];        // 16KB per buffer
    int arow = m0 + w*16 + lr;
    const bf16* Ab = embf + (size_t)arow*1024 + ko*8;
    for (int sub = 0; sub < 4; sub++){
        int c0 = sub*256;
        const bf16* sp[4];
        #pragma unroll
        for (int p = 0; p < 4; p++){
            int s = p*256 + tid;
            int f = s >> 6, sl = s & 63;
            int col = c0 + f*16 + (sl & 15);
            sp[p] = poW1 + (size_t)col*2048 + 1024 + (sl >> 4)*8;
        }
        // prologue: stage tile 0
        #pragma unroll
        for (int p = 0; p < 4; p++) gload16(sp[p], &Bl[0][(p*256 + tid)*8]);
        bf16x8 a = *(const bf16x8*)(Ab);
        __syncthreads();
        f32x4 acc[16] = {};
        for (int kt = 0; kt < 32; ++kt){
            int cur = kt & 1;
            if (kt < 31){
                int k1 = (kt+1)*32;
                #pragma unroll
                for (int p = 0; p < 4; p++)
                    gload16(sp[p] + k1, &Bl[cur ^ 1][(p*256 + tid)*8]);
            }
            bf16x8 an = a;
            if (kt < 31) an = *(const bf16x8*)(Ab + (kt+1)*32);
            const bf16* Br = &Bl[cur][0];
            #pragma unroll
            for (int f = 0; f < 16; f++){
                bf16x8 b = *(const bf16x8*)(&Br[((f*64) + l)*8]);
                acc[f] = __builtin_amdgcn_mfma_f32_16x16x32_bf16(a, b, acc[f], 0,0,0);
            }
            __syncthreads();
            a = an;
        }
        // epilogue: repack via LDS, full-line stores
        bf16* outT = &Bl[0][0];             // [64][256] overlay (32KB)
        #pragma unroll
        for (int f = 0; f < 16; f++){
            int col = f*16 + lr;
            #pragma unroll
            for (int r = 0; r < 4; r++)
                outT[(w*16 + ko*4 + r)*256 + col] = (bf16)acc[f][r];
        }
        __syncthreads();
        {
            int colb = (tid & 31)*8;
            int rbase = tid >> 5;
            #pragma unroll
            for (int j = 0; j < 8; j++){
                int row = rbase + j*8;
                *(uint4*)&part[(size_t)(m0 + row)*1024 + c0 + colb] =
                    *(const uint4*)&outT[row*256 + colb];
            }
        }
        __syncthreads();
    }
}

// ---------------- fused persistent step loop -------------------------------
// 512 blocks x 256 threads, 2 blocks/CU. Cross-block handoff goes through
// t-indexed slabs written with write-through sysstores; consumers use NORMAL
// cached loads (addresses are virgin -> no stale L2 lines; L2 absorbs the
// n-slice fanout). Embed-partial reads of slabs use sysloads so slab
// addresses are never pre-cached before their deter overwrite.
struct SArgs {
    bf16* __restrict__ h_buf;     // fallback single h buffer (HS=false)
    bf16* __restrict__ hsl;       // 64 x 2MB t-indexed h slabs (HS=true)
    const bf16* __restrict__ dbuf0;
    const bf16* __restrict__ wih;
    const bf16* __restrict__ whh;
    const float* __restrict__ bih;
    const float* __restrict__ bhh;
    const float* __restrict__ deter0;
    float* __restrict__ dF0;
    float* __restrict__ dF1;
    float* __restrict__ out;
    const bf16* __restrict__ poW1;
    const float* __restrict__ pob1;
    bf16* __restrict__ partial;
    bf16* __restrict__ po1h;
    const bf16* __restrict__ poW2;
    const float* __restrict__ pob2;
    const float* __restrict__ noise_po;
    const float* __restrict__ actions;
    const bf16* __restrict__ aspW;
    const float* __restrict__ aspb;
    bf16* __restrict__ dall0;
    unsigned* __restrict__ bar;
};

template<bool HS>
__global__ __launch_bounds__(256, 2) void k_steps(SArgs a){
    __shared__ __align__(16) char smem[24576];   // max over phases (GRU: 2x12KB)
    int bid = blockIdx.x;
    int tid = threadIdx.x;
    int w = tid >> 6, l = tid & 63;
    int lr = l & 15, ko = l >> 4;

    // ---- t-invariant GRU/po1 geometry: 32 n-slices x 16 m-blocks ----
    int n = bid & 31, mb = bid >> 5;
    int j0 = n*32, m0g = mb*64;
    const bf16* spg[3];
    #pragma unroll
    for (int p = 0; p < 3; p++){
        int s = p*256 + tid;
        int f = s >> 6, sl = s & 63;
        int g = f >> 1, cfl = f & 1;
        int col = j0 + cfl*16 + (sl & 15);
        const bf16* base = (g < 3) ? a.wih : a.whh;
        int gg = (g < 3) ? g : g - 3;
        spg[p] = base + (size_t)(gg*1024 + col)*1024 + (sl >> 4)*8;
    }
    int arow = m0g + w*16 + lr;
    const bf16* spp;
    {   int f = tid >> 6, sl = tid & 63;
        int ksub = f >> 1, cfl = f & 1;
        int col = j0 + cfl*16 + (sl & 15);
        spp = a.poW1 + (size_t)col*2048 + ksub*32 + (sl >> 4)*8;
    }

    int sync_id = 0;
    for (int t = 0; t < T_; t++){
        // ================= phase 1: GRU =================
        {
            const float* dprev_f = (t == 0) ? a.deter0 : ((t & 1) ? a.dF1 : a.dF0);
            float* dcur_f = (((t+1) & 1)) ? a.dF1 : a.dF0;
            float* dout_t = a.out + DOFF_ + (size_t)t*D_;
            bf16* dall_t = (t == 0) ? a.dall0 : a.partial + (size_t)(t-1)*SLAB_;
            // deter(t-1) source: fresh slab (cached) / cvt'd deter0
            const bf16* dAb = (t == 0) ? a.dbuf0 :
                              (t == 1) ? a.dall0 : a.partial + (size_t)(t-2)*SLAB_;
            const bf16* hAb = HS ? (a.hsl + (size_t)t*SLAB_) : a.h_buf;
            const bf16* dA = dAb + (size_t)arow*1024 + ko*8;
            const bf16* hA = hAb + (size_t)arow*1024 + ko*8;
            bf16 (*Bl)[6144] = (bf16(*)[6144])smem;
            #pragma unroll
            for (int p = 0; p < 3; p++) gload16(spg[p], &Bl[0][(p*256 + tid)*8]);
            bf16x8 aH = HS ? *(const bf16x8*)(hA) : ld_sys128(hA);
            bf16x8 aD = *(const bf16x8*)(dA);
            __syncthreads();
            f32x4 acc[6][2] = {};
            for (int kt = 0; kt < 32; ++kt){
                int cur = kt & 1;
                if (kt < 31){
                    int k1 = (kt+1)*32;
                    #pragma unroll
                    for (int p = 0; p < 3; p++)
                        gload16(spg[p] + k1, &Bl[cur ^ 1][(p*256 + tid)*8]);
                }
                bf16x8 aHn = aH, aDn = aD;
                if (kt < 31){
                    aHn = HS ? *(const bf16x8*)(hA + (kt+1)*32)
                             : ld_sys128(hA + (kt+1)*32);
                    aDn = *(const bf16x8*)(dA + (kt+1)*32);
                }
                const bf16* Br = &Bl[cur][0];
                #pragma unroll
                for (int g = 0; g < 6; g++){
                    #pragma unroll
                    for (int cfl = 0; cfl < 2; cfl++){
                        bf16x8 b = *(const bf16x8*)(&Br[((g*2 + cfl)*64 + l)*8]);
                        acc[g][cfl] = __builtin_amdgcn_mfma_f32_16x16x32_bf16(
                            g < 3 ? aH : aD, b, acc[g][cfl], 0,0,0);
                    }
                }
                __syncthreads();
                aH = aHn; aD = aDn;
            }
            bf16 (*rp)[32] = (bf16(*)[32])smem;       // 4KB repack tile
            #pragma unroll
            for (int cfl = 0; cfl < 2; cfl++){
                int j = j0 + cfl*16 + lr;
                float bir = a.bih[j],      bhr = a.bhh[j];
                float biz = a.bih[1024+j], bhz = a.bhh[1024+j];
                float bin = a.bih[2048+j], bhn = a.bhh[2048+j];
                #pragma unroll
                for (int r = 0; r < 4; r++){
                    int m = m0g + w*16 + ko*4 + r;
                    float ir  = acc[0][cfl][r] + bir;
                    float iz  = acc[1][cfl][r] + biz;
                    float in_ = acc[2][cfl][r] + bin;
                    float hr  = acc[3][cfl][r] + bhr;
                    float hz  = acc[4][cfl][r] + bhz;
                    float hn  = acc[5][cfl][r] + bhn;
                    float rg = sigmoidf_(ir + hr);
                    float zg = sigmoidf_(iz + hz);
                    float ng = tanhf(in_ + rg*hn);
                    float dp = dprev_f[(size_t)m*D_ + j];
                    float dn = (1.f - zg)*ng + zg*dp;
                    dout_t[(size_t)m*(T_*D_) + j] = dn;
                    dcur_f[(size_t)m*D_ + j] = dn;
                    rp[w*16 + ko*4 + r][cfl*16 + lr] = (bf16)dn;
                }
            }
            __syncthreads();
            {   // contiguous 16B/thread write-through stores to the t-slab
                int row = tid >> 2, c8 = (tid & 3)*8;
                const u64* q = (const u64*)&rp[row][c8];
                bf16* gp = dall_t + (size_t)(m0g + row)*1024 + j0 + c8;
                st_sys64(gp,     q[0]);
                st_sys64(gp + 4, q[1]);
            }
        }
        gridbar(a.bar, sync_id++);
        // ================= phase 2: po1 =================
        {
            const bf16* Apo = (t == 0) ? a.dall0 : a.partial + (size_t)(t-1)*SLAB_;
            bf16 (*Bl)[2048] = (bf16(*)[2048])smem;
            const bf16* A = Apo + (size_t)arow*1024 + ko*8;
            gload16(spp, &Bl[0][tid*8]);
            bf16x8 a0 = *(const bf16x8*)(A);
            bf16x8 a1 = *(const bf16x8*)(A + 32);
            __syncthreads();
            f32x4 acc[2] = {};
            for (int kt = 0; kt < 16; ++kt){
                int cur = kt & 1;
                if (kt < 15) gload16(spp + (kt+1)*64, &Bl[cur ^ 1][tid*8]);
                bf16x8 a0n = a0, a1n = a1;
                if (kt < 15){
                    a0n = *(const bf16x8*)(A + (kt+1)*64);
                    a1n = *(const bf16x8*)(A + (kt+1)*64 + 32);
                }
                const bf16* Br = &Bl[cur][0];
                #pragma unroll
                for (int ksub = 0; ksub < 2; ksub++){
                    #pragma unroll
                    for (int cfl = 0; cfl < 2; cfl++){
                        bf16x8 b = *(const bf16x8*)(&Br[((ksub*2 + cfl)*64 + l)*8]);
                        acc[cfl] = __builtin_amdgcn_mfma_f32_16x16x32_bf16(
                            ksub ? a1 : a0, b, acc[cfl], 0,0,0);
                    }
                }
                __syncthreads();
                a0 = a0n; a1 = a1n;
            }
            // stage embed-partial tile via SYSLOAD (keeps slab t uncached in L2)
            bf16 (*rp)[32] = (bf16(*)[32])smem;            // 0..4KB
            bf16* emb = (bf16*)(smem + 4096);              // 4..8KB [64][32]
            {
                int row = tid >> 2, colb = (tid & 3)*8;
                *(bf16x8*)&emb[row*32 + colb] =
                    ld_sys128(a.partial + ((size_t)t*B_ + m0g + row)*1024 + j0 + colb);
            }
            __syncthreads();
            #pragma unroll
            for (int cfl = 0; cfl < 2; cfl++){
                int col = j0 + cfl*16 + lr;
                float bb = a.pob1[col];
                #pragma unroll
                for (int r = 0; r < 4; r++){
                    int lrow = w*16 + ko*4 + r;
                    float v = acc[cfl][r] + bb + (float)emb[lrow*32 + cfl*16 + lr];
                    rp[lrow][cfl*16 + lr] = (bf16)eluf(v);
                }
            }
            __syncthreads();
            {
                int row = tid >> 2, c8 = (tid & 3)*8;
                const u64* q = (const u64*)&rp[row][c8];
                bf16* gp = a.po1h + (size_t)(m0g + row)*1024 + j0 + c8;
                st_sys64(gp,     q[0]);
                st_sys64(gp + 4, q[1]);
            }
        }
        gridbar(a.bar, sync_id++);
        // ================= phase 3: po_out (64 blocks) =================
        if (bid < 64){
            int m0 = bid << 4;
            float (*ps)[16][68] = (float(*)[16][68])smem;           // 17408 B
            bf16 (*smA)[88] = (bf16(*)[88])(smem + 17408);          // 2816 B
            // ping-pong cross-lane repack tile; barrier between write & read
            bf16 (*hrep)[2][16][16] = (bf16(*)[2][16][16])(smem + 20224); // 4096 B
            bf16* hd = HS ? (a.hsl + (size_t)(t+1)*SLAB_) : a.h_buf;
            int ks = w * 256;
            f32x4 acc[4] = {};
            const bf16* apo = a.po1h + (size_t)(m0 + lr)*1024 + ks + ko*8;
            bf16x8 a2 = ld_sys128(apo);
            #pragma unroll
            for (int kk = 0; kk < 8; kk++){
                bf16x8 a2n = a2;
                if (kk < 7) a2n = ld_sys128(apo + (kk+1)*32);
                int k = kk*32;
                #pragma unroll
                for (int cf = 0; cf < 4; cf++){
                    bf16x8 b2 = *(const bf16x8*)(a.poW2 + (size_t)(cf*16+lr)*1024 + ks + k + ko*8);
                    acc[cf] = __builtin_amdgcn_mfma_f32_16x16x32_bf16(a2, b2, acc[cf], 0,0,0);
                }
                a2 = a2n;
            }
            #pragma unroll
            for (int cf = 0; cf < 4; cf++){
                int col = cf*16 + lr;
                #pragma unroll
                for (int r = 0; r < 4; r++) ps[w][ko*4+r][col] = acc[cf][r];
            }
            __syncthreads();
            for (int it = 0; it < 2; it++){
                int idx2 = tid + it*256;
                int s = idx2 & 31, mm = idx2 >> 5;
                int mg = m0 + mm;
                float qm  = ps[0][mm][s]    + ps[1][mm][s]    + ps[2][mm][s]    + ps[3][mm][s]    + a.pob2[s];
                float qls = ps[0][mm][32+s] + ps[1][mm][32+s] + ps[2][mm][32+s] + ps[3][mm][32+s] + a.pob2[32+s];
                float qstd = softplusf_(qls) + 0.1f;
                size_t no = (size_t)mg*(T_*S_) + (size_t)t*S_ + s;
                float qst = qm + a.noise_po[no]*qstd;
                a.out[0*(size_t)CH_ + no] = qm;
                a.out[1*(size_t)CH_ + no] = qstd;
                a.out[2*(size_t)CH_ + no] = qst;
                smA[mm][s] = (bf16)qst;
                if (t + 1 < T_)
                    smA[mm][32+s] = (bf16)a.actions[(size_t)mg*(T_*S_) + (size_t)(t+1)*S_ + s];
            }
            __syncthreads();
            if (t + 1 < T_){
                for (int c2 = 0; c2 < 16; c2++){
                    int nb = w*256 + c2*16;
                    int pb = c2 & 1;
                    f32x4 a2v = {0.f, 0.f, 0.f, 0.f};
                    #pragma unroll
                    for (int kk = 0; kk < 2; kk++){
                        bf16x8 av = *(const bf16x8*)(&smA[lr][kk*32 + ko*8]);
                        bf16x8 bv = *(const bf16x8*)(a.aspW + (size_t)(nb+lr)*64 + kk*32 + ko*8);
                        a2v = __builtin_amdgcn_mfma_f32_16x16x32_bf16(av, bv, a2v, 0,0,0);
                    }
                    int n2 = nb + lr;
                    float bb = a.aspb[n2];
                    #pragma unroll
                    for (int r = 0; r < 4; r++)
                        hrep[w][pb][ko*4 + r][lr] = (bf16)eluf(a2v[r] + bb);
                    __syncthreads();   // cross-lane LDS handoff needs a barrier
                    u64 q = *(const u64*)&hrep[w][pb][l >> 2][(l & 3)*4];
                    st_sys64(&hd[(size_t)(m0 + (l >> 2))*1024 + nb + (l & 3)*4], q);
                }
            }
        }
        gridbar(a.bar, sync_id++);
    }
}

// ---------------- batched prior path (async-staged B, padded rp1s) ---------
// 1024 blocks x 64 rows. rp1 (4 subtiles) -> rp1s -> rp2 -> sample.
__global__ __launch_bounds__(256) void k_prior(
        const bf16* __restrict__ dallP, const bf16* __restrict__ dall0,
        const bf16* __restrict__ rpW1, const float* __restrict__ rpb1,
        const bf16* __restrict__ rpW2, const float* __restrict__ rpb2,
        const float* __restrict__ noise_pr,
        float* __restrict__ out){
    int bid = blockIdx.x;
    int sl = bid >> 4;
    int b0 = (bid & 15)*64;
    int t  = (sl == 63) ? 0 : sl + 1;
    const bf16* Abase = (sl == 63) ? dall0 : dallP + (size_t)sl*SLAB_;
    int tid = threadIdx.x;
    int w = tid >> 6, l = tid & 63;
    int lr = l & 15, ko = l >> 4;
    __shared__ bf16 Bl[2][8192];       // 16KB per buffer
    __shared__ bf16 rp1s[64][264];     // padded (+8)
    const bf16* Ar = Abase + (size_t)(b0 + w*16 + lr)*1024 + ko*8;
    f32x4 acc2[4] = {};
    const bf16* sp[4];
    {   // sp for subtile 0
        #pragma unroll
        for (int p = 0; p < 4; p++){
            int s = p*256 + tid;
            int f = s >> 6, sl2 = s & 63;
            int col = f*16 + (sl2 & 15);
            sp[p] = rpW1 + (size_t)col*1024 + (sl2 >> 4)*8;
        }
    }
    // prologue: stage subtile-0 tile-0
    #pragma unroll
    for (int p = 0; p < 4; p++) gload16(sp[p], &Bl[0][(p*256 + tid)*8]);
    __syncthreads();
    for (int sub = 0; sub < 4; sub++){
        int c0 = sub*256;
        f32x4 acc[16] = {};
        bf16x8 a = *(const bf16x8*)(Ar);
        for (int kt = 0; kt < 32; ++kt){
            int cur = kt & 1;
            if (kt < 31){
                int k1 = (kt+1)*32;
                #pragma unroll
                for (int p = 0; p < 4; p++)
                    gload16(sp[p] + k1, &Bl[cur ^ 1][(p*256 + tid)*8]);
            }
            bf16x8 an = a;
            if (kt < 31) an = *(const bf16x8*)(Ar + (kt+1)*32);
            const bf16* Br = &Bl[cur][0];
            #pragma unroll
            for (int f = 0; f < 16; f++){
                bf16x8 b = *(const bf16x8*)(&Br[((f*64) + l)*8]);
                acc[f] = __builtin_amdgcn_mfma_f32_16x16x32_bf16(a, b, acc[f], 0,0,0);
            }
            __syncthreads();
            a = an;
        }
        // tail: issue next subtile's first tile into Bl[0] (hides under rp2)
        if (sub < 3){
            int c1 = c0 + 256;
            #pragma unroll
            for (int p = 0; p < 4; p++){
                int s = p*256 + tid;
                int f = s >> 6, sl2 = s & 63;
                int col = c1 + f*16 + (sl2 & 15);
                sp[p] = rpW1 + (size_t)col*1024 + (sl2 >> 4)*8;
                gload16(sp[p], &Bl[0][(p*256 + tid)*8]);
            }
        }
        // rp1 epilogue -> rp1s (padded)
        #pragma unroll
        for (int f = 0; f < 16; f++){
            int col = f*16 + lr;
            float bb = rpb1[c0 + col];
            #pragma unroll
            for (int r = 0; r < 4; r++)
                rp1s[w*16 + ko*4 + r][col] = (bf16)eluf(acc[f][r] + bb);
        }
        __syncthreads();
        // rp2 partial GEMM over this 256-col K-slice
        #pragma unroll
        for (int kk = 0; kk < 8; kk++){
            int k = kk*32;
            bf16x8 a2 = *(const bf16x8*)(&rp1s[w*16 + lr][k + ko*8]);
            #pragma unroll
            for (int cf = 0; cf < 4; cf++){
                bf16x8 b2 = *(const bf16x8*)(rpW2 + (size_t)(cf*16+lr)*1024 + c0 + k + ko*8);
                acc2[cf] = __builtin_amdgcn_mfma_f32_16x16x32_bf16(a2, b2, acc2[cf], 0,0,0);
            }
        }
        __syncthreads();   // rp1s reads done + Bl[0] stage drained (vmcnt at barrier)
    }
    #pragma unroll
    for (int cf = 0; cf < 2; cf++){
        int s = cf*16 + lr;
        float b1 = rpb2[s], b2 = rpb2[32+s];
        #pragma unroll
        for (int r = 0; r < 4; r++){
            int row = w*16 + ko*4 + r;
            float pm  = acc2[cf][r]   + b1;
            float pls = acc2[cf+2][r] + b2;
            float pstd = softplusf_(pls) + 0.1f;
            size_t no = (size_t)(b0 + row)*2048 + (size_t)t*32 + s;
            float pst = pm + noise_pr[no]*pstd;
            out[3*(size_t)CH_ + no] = pm;
            out[4*(size_t)CH_ + no] = pstd;
            out[5*(size_t)CH_ + no] = pst;
        }
    }
}

extern "C" void kernel_launch(void* const* d_in, const int* in_sizes, int n_in,
                              void* d_out, int out_size, void* d_ws, size_t ws_size,
                              hipStream_t stream) {
    const float* embeds   = (const float*)d_in[0];
    const float* actions  = (const float*)d_in[1];
    const float* deter0   = (const float*)d_in[2];
    const float* stoch0   = (const float*)d_in[3];
    const float* noise_pr = (const float*)d_in[4];
    const float* noise_po = (const float*)d_in[5];
    const float* asp_W    = (const float*)d_in[6];
    const float* asp_b    = (const float*)d_in[7];
    const float* w_ih     = (const float*)d_in[8];
    const float* w_hh     = (const float*)d_in[9];
    const float* b_ih     = (const float*)d_in[10];
    const float* b_hh     = (const float*)d_in[11];
    const float* rp_W1    = (const float*)d_in[12];
    const float* rp_b1    = (const float*)d_in[13];
    const float* rp_W2    = (const float*)d_in[14];
    const float* rp_b2    = (const float*)d_in[15];
    const float* po_W1    = (const float*)d_in[16];
    const float* po_b1    = (const float*)d_in[17];
    const float* po_W2    = (const float*)d_in[18];
    const float* po_b2    = (const float*)d_in[19];
    float* out = (float*)d_out;

    char* ws = (char*)d_ws;
    const size_t MB = 1024*1024;
    bf16*  h_buf   = (bf16*)(ws + 0*MB);
    bf16*  dbuf0   = (bf16*)(ws + 2*MB);
    bf16*  po1h    = (bf16*)(ws + 6*MB);
    float* dF0     = (float*)(ws + 10*MB);
    float* dF1     = (float*)(ws + 14*MB);
    bf16*  w_ih_b  = (bf16*)(ws + 18*MB);
    bf16*  w_hh_b  = (bf16*)(ws + 24*MB);
    bf16*  rpW1_b  = (bf16*)(ws + 30*MB);
    bf16*  poW1_b  = (bf16*)(ws + 32*MB);
    bf16*  rpW2_b  = (bf16*)(ws + 36*MB);
    bf16*  poW2_b  = (bf16*)(ws + 36*MB + 256*1024);
    bf16*  aspW_b  = (bf16*)(ws + 36*MB + 512*1024);
    unsigned* bar  = (unsigned*)(ws + 37*MB);              // 192 x 64B counters
    bf16*  dall0   = (bf16*)(ws + 38*MB);                  // 2MB: deter t=0 slab
    bf16*  partial = (bf16*)(ws + 40*MB);                  // 128MB, [t][b][n] slabs
    bf16*  hsl     = (bf16*)(ws + 168*MB);                 // 128MB, t-indexed h slabs
    bf16*  embf    = (bf16*)(out + DOFF_);                 // scratch in d_out deter region

    bool hs = ws_size >= (size_t)296*MB;

    hipMemsetAsync(bar, 0, 192*64, stream);

    auto cvt = [&](const float* s, bf16* d, int n){
        k_cvt<<<(n/4 + 255)/256, 256, 0, stream>>>(s, d, n);
    };
    cvt(w_ih,  w_ih_b, 3072*1024);
    cvt(w_hh,  w_hh_b, 3072*1024);
    cvt(rp_W1, rpW1_b, 1024*1024);
    cvt(po_W1, poW1_b, 1024*2048);
    cvt(rp_W2, rpW2_b, 64*1024);
    cvt(po_W2, poW2_b, 64*1024);
    cvt(asp_W, aspW_b, 1024*64);
    cvt(deter0, dbuf0, 1024*1024);
    k_h0<<<1024, 256, 0, stream>>>(stoch0, actions, asp_W, asp_b,
                                   hs ? hsl : h_buf);
    k_cvt_tr<<<B_*T_, 256, 0, stream>>>(embeds, embf);
    k_pre<<<1024, 256, 0, stream>>>(embf, poW1_b, partial);

    SArgs sa;
    sa.h_buf = h_buf;  sa.hsl = hsl;  sa.dbuf0 = dbuf0;
    sa.wih = w_ih_b;   sa.whh = w_hh_b;
    sa.bih = b_ih;     sa.bhh = b_hh;
    sa.deter0 = deter0;
    sa.dF0 = dF0;      sa.dF1 = dF1;
    sa.out = out;
    sa.poW1 = poW1_b;  sa.pob1 = po_b1;
    sa.partial = partial;
    sa.po1h = po1h;
    sa.poW2 = poW2_b;  sa.pob2 = po_b2;
    sa.noise_po = noise_po;
    sa.actions = actions;
    sa.aspW = aspW_b;  sa.aspb = asp_b;
    sa.dall0 = dall0;
    sa.bar = bar;
    if (hs) k_steps<true><<<512, 256, 0, stream>>>(sa);
    else    k_steps<false><<<512, 256, 0, stream>>>(sa);

    k_prior<<<1024, 256, 0, stream>>>(partial, dall0, rpW1_b, rp_b1,
                                      rpW2_b, rp_b2, noise_pr, out);
}

// Round 8
// 8662.888 us; speedup vs baseline: 1.6921x; 1.2893x over previous
//
#include <hip/hip_runtime.h>
#include <hip/hip_bf16.h>
#include <math.h>

typedef __bf16 bf16;
typedef bf16 bf16x8 __attribute__((ext_vector_type(8)));
typedef float f32x4 __attribute__((ext_vector_type(4)));
typedef unsigned long long u64;

#define B_ 1024
#define T_ 64
#define D_ 1024
#define S_ 32
#define CH_ (B_*T_*S_)
#define DOFF_ ((size_t)6*CH_)
#define NBLK_ 512u
#define SLAB_ ((size_t)1048576)   // bf16 elems per t-slab (2MB)

__device__ __forceinline__ float eluf(float x){ return x > 0.f ? x : expm1f(x); }
__device__ __forceinline__ float sigmoidf_(float x){ return 1.f/(1.f+expf(-x)); }
__device__ __forceinline__ float softplusf_(float x){
    return x > 0.f ? x + log1pf(expf(-x)) : log1pf(expf(x));
}

// async global->LDS, 16B per lane; LDS dest must be linear in lane order
__device__ __forceinline__ void gload16(const bf16* g, bf16* l){
    __builtin_amdgcn_global_load_lds(
        (const __attribute__((address_space(1))) void*)(g),
        (__attribute__((address_space(3))) void*)(l), 16, 0, 0);
}

// ---- system-scope (LLC) accesses: write-through stores for handoff, ------
// uncached loads only where cached would be stale-prone (embed slabs, po1h).
__device__ __forceinline__ u64 ld_sys64(const void* p){
    return __hip_atomic_load((const u64*)p, __ATOMIC_RELAXED,
                             __HIP_MEMORY_SCOPE_SYSTEM);
}
__device__ __forceinline__ void st_sys64(void* p, u64 v){
    __hip_atomic_store((u64*)p, v, __ATOMIC_RELAXED,
                       __HIP_MEMORY_SCOPE_SYSTEM);
}
__device__ __forceinline__ bf16x8 ld_sys128(const bf16* p){
    union { u64 q[2]; bf16x8 v; } u;
    u.q[0] = ld_sys64(p);
    u.q[1] = ld_sys64(p + 4);
    return u.v;
}

// Broadcast grid barrier (R6-proven relaxed semantics, decontended):
// all leaders do ONE relaxed add to the root; ONLY block 0 polls the root,
// then writes 8 per-XCD go-words (64B-strided lines); other leaders poll
// their XCD's go word (load-only, 64 pollers/line). No fences, no cache
// walks -- data moves via write-through stores drained by __syncthreads'
// vmcnt(0) before arrival (validated R5/R6/R7).
__device__ __forceinline__ void gridbar(unsigned* __restrict__ bar, int id){
    __syncthreads();
    if (threadIdx.x == 0){
        unsigned* root = bar + (id << 4);
        __hip_atomic_fetch_add(root, 1u, __ATOMIC_RELAXED, __HIP_MEMORY_SCOPE_AGENT);
        if (blockIdx.x == 0){
            while (__hip_atomic_load(root, __ATOMIC_RELAXED,
                                     __HIP_MEMORY_SCOPE_AGENT) < NBLK_)
                __builtin_amdgcn_s_sleep(2);
            unsigned* gobase = bar + 4096;          // +16KB
            #pragma unroll
            for (int g = 0; g < 8; g++)
                __hip_atomic_store(gobase + ((id*8 + g) << 4), 1u,
                                   __ATOMIC_RELAXED, __HIP_MEMORY_SCOPE_AGENT);
        } else {
            unsigned* gow = bar + 4096 + ((id*8 + ((int)blockIdx.x & 7)) << 4);
            while (__hip_atomic_load(gow, __ATOMIC_RELAXED,
                                     __HIP_MEMORY_SCOPE_AGENT) == 0u)
                __builtin_amdgcn_s_sleep(2);
        }
    }
    __syncthreads();
    asm volatile("" ::: "memory");
}

// ---------------- fp32 -> bf16 conversion ----------------------------------
__global__ __launch_bounds__(256) void k_cvt(const float* __restrict__ src,
                                             bf16* __restrict__ dst, int n){
    int i = (blockIdx.x*256 + threadIdx.x)*4;
    if (i < n){
        float4 v = *reinterpret_cast<const float4*>(src + i);
        dst[i+0] = (bf16)v.x; dst[i+1] = (bf16)v.y;
        dst[i+2] = (bf16)v.z; dst[i+3] = (bf16)v.w;
    }
}

// ---------------- embeds fp32 [b][t][e] -> bf16 [t][b][e] ------------------
__global__ __launch_bounds__(256) void k_cvt_tr(const float* __restrict__ src,
                                                bf16* __restrict__ dst){
    int row = blockIdx.x;                 // flat b*T + t
    int b = row >> 6, t = row & 63;
    const float* s = src + (size_t)row*1024;
    bf16* d = dst + ((size_t)t*B_ + b)*1024;
    int i = threadIdx.x*4;
    float4 v = *reinterpret_cast<const float4*>(s + i);
    d[i+0] = (bf16)v.x; d[i+1] = (bf16)v.y;
    d[i+2] = (bf16)v.z; d[i+3] = (bf16)v.w;
}

// ---------------- h0 = elu([stoch0 | action_0] @ asp_W^T + asp_b) ----------
__global__ __launch_bounds__(256) void k_h0(const float* __restrict__ stoch0,
                                            const float* __restrict__ actions,
                                            const float* __restrict__ aspW,
                                            const float* __restrict__ aspb,
                                            bf16* __restrict__ h_dst){
    int m = blockIdx.x;
    __shared__ float av[64];
    int tid = threadIdx.x;
    if (tid < 32)      av[tid] = stoch0[m*S_ + tid];
    else if (tid < 64) av[tid] = actions[(size_t)m*T_*S_ + (tid-32)];
    __syncthreads();
    for (int c = 0; c < 4; c++){
        int n = c*256 + tid;
        float s = aspb[n];
        const float* wr = aspW + n*64;
        #pragma unroll 8
        for (int k = 0; k < 64; k++) s += av[k]*wr[k];
        h_dst[(size_t)m*D_ + n] = (bf16)eluf(s);
    }
}

// ---------------- embed GEMM: partial[t][b][n] (async-staged) --------------
__global__ __launch_bounds__(256) void k_pre(const bf16* __restrict__ embf,
                                             const bf16* __restrict__ poW1,
                                             bf16* __restrict__ part){
    int m0 = blockIdx.x * 64;
    int tid = threadIdx.x;
    int w = tid >> 6, l = tid & 63;
    int lr = l & 15, ko = l >> 4;
    __shared__ bf16 Bl[2][16*64*8];        // 16KB per buffer
    int arow = m0 + w*16 + lr;
    const bf16* Ab = embf + (size_t)arow*1024 + ko*8;
    for (int sub = 0; sub < 4; sub++){
        int c0 = sub*256;
        const bf16* sp[4];
        #pragma unroll
        for (int p = 0; p < 4; p++){
            int s = p*256 + tid;
            int f = s >> 6, sl = s & 63;
            int col = c0 + f*16 + (sl & 15);
            sp[p] = poW1 + (size_t)col*2048 + 1024 + (sl >> 4)*8;
        }
        // prologue: stage tile 0
        #pragma unroll
        for (int p = 0; p < 4; p++) gload16(sp[p], &Bl[0][(p*256 + tid)*8]);
        bf16x8 a = *(const bf16x8*)(Ab);
        __syncthreads();
        f32x4 acc[16] = {};
        for (int kt = 0; kt < 32; ++kt){
            int cur = kt & 1;
            if (kt < 31){
                int k1 = (kt+1)*32;
                #pragma unroll
                for (int p = 0; p < 4; p++)
                    gload16(sp[p] + k1, &Bl[cur ^ 1][(p*256 + tid)*8]);
            }
            bf16x8 an = a;
            if (kt < 31) an = *(const bf16x8*)(Ab + (kt+1)*32);
            const bf16* Br = &Bl[cur][0];
            #pragma unroll
            for (int f = 0; f < 16; f++){
                bf16x8 b = *(const bf16x8*)(&Br[((f*64) + l)*8]);
                acc[f] = __builtin_amdgcn_mfma_f32_16x16x32_bf16(a, b, acc[f], 0,0,0);
            }
            __syncthreads();
            a = an;
        }
        // epilogue: repack via LDS, full-line stores
        bf16* outT = &Bl[0][0];             // [64][256] overlay (32KB)
        #pragma unroll
        for (int f = 0; f < 16; f++){
            int col = f*16 + lr;
            #pragma unroll
            for (int r = 0; r < 4; r++)
                outT[(w*16 + ko*4 + r)*256 + col] = (bf16)acc[f][r];
        }
        __syncthreads();
        {
            int colb = (tid & 31)*8;
            int rbase = tid >> 5;
            #pragma unroll
            for (int j = 0; j < 8; j++){
                int row = rbase + j*8;
                *(uint4*)&part[(size_t)(m0 + row)*1024 + c0 + colb] =
                    *(const uint4*)&outT[row*256 + colb];
            }
        }
        __syncthreads();
    }
}

// ---------------- fused persistent step loop -------------------------------
// 512 blocks x 256 threads, 2 blocks/CU. BK=64 GRU / BK=128 po1: double
// K-chunk per LDS buffer halves barrier-drain frequency and doubles
// in-flight fetch bytes (MLP) in the latency-bound K-loops.
struct SArgs {
    bf16* __restrict__ h_buf;     // fallback single h buffer (HS=false)
    bf16* __restrict__ hsl;       // 64 x 2MB t-indexed h slabs (HS=true)
    const bf16* __restrict__ dbuf0;
    const bf16* __restrict__ wih;
    const bf16* __restrict__ whh;
    const float* __restrict__ bih;
    const float* __restrict__ bhh;
    const float* __restrict__ deter0;
    float* __restrict__ dF0;
    float* __restrict__ dF1;
    float* __restrict__ out;
    const bf16* __restrict__ poW1;
    const float* __restrict__ pob1;
    bf16* __restrict__ partial;
    bf16* __restrict__ po1h;
    const bf16* __restrict__ poW2;
    const float* __restrict__ pob2;
    const float* __restrict__ noise_po;
    const float* __restrict__ actions;
    const bf16* __restrict__ aspW;
    const float* __restrict__ aspb;
    bf16* __restrict__ dall0;
    unsigned* __restrict__ bar;
};

template<bool HS>
__global__ __launch_bounds__(256, 2) void k_steps(SArgs a){
    __shared__ __align__(16) char smem[49152];   // GRU: 2 x 24KB BK=64 buffers
    int bid = blockIdx.x;
    int tid = threadIdx.x;
    int w = tid >> 6, l = tid & 63;
    int lr = l & 15, ko = l >> 4;

    // ---- t-invariant GRU/po1 geometry: 32 n-slices x 16 m-blocks ----
    int n = bid & 31, mb = bid >> 5;
    int j0 = n*32, m0g = mb*64;
    // GRU B staging: 24 (g,cfl,kh) fragments, 6 pointers
    const bf16* spg[6];
    #pragma unroll
    for (int p = 0; p < 6; p++){
        int s = p*256 + tid;
        int f = s >> 6, sl = s & 63;
        int g = f >> 2, cfl = (f & 3) >> 1, kh = f & 1;
        int col = j0 + cfl*16 + (sl & 15);
        const bf16* base = (g < 3) ? a.wih : a.whh;
        int gg = (g < 3) ? g : g - 3;
        spg[p] = base + (size_t)(gg*1024 + col)*1024 + kh*32 + (sl >> 4)*8;
    }
    int arow = m0g + w*16 + lr;
    // po1 B staging: 8 (ksub,cfl) fragments, 2 pointers
    const bf16* spp[2];
    #pragma unroll
    for (int p = 0; p < 2; p++){
        int s = p*256 + tid;
        int f = s >> 6, sl = s & 63;
        int ksub = f >> 1, cfl = f & 1;
        int col = j0 + cfl*16 + (sl & 15);
        spp[p] = a.poW1 + (size_t)col*2048 + ksub*32 + (sl >> 4)*8;
    }

    int sync_id = 0;
    for (int t = 0; t < T_; t++){
        // ================= phase 1: GRU (BK=64, 16 iters) =================
        {
            const float* dprev_f = (t == 0) ? a.deter0 : ((t & 1) ? a.dF1 : a.dF0);
            float* dcur_f = (((t+1) & 1)) ? a.dF1 : a.dF0;
            float* dout_t = a.out + DOFF_ + (size_t)t*D_;
            bf16* dall_t = (t == 0) ? a.dall0 : a.partial + (size_t)(t-1)*SLAB_;
            const bf16* dAb = (t == 0) ? a.dbuf0 :
                              (t == 1) ? a.dall0 : a.partial + (size_t)(t-2)*SLAB_;
            const bf16* hAb = HS ? (a.hsl + (size_t)t*SLAB_) : a.h_buf;
            const bf16* dA = dAb + (size_t)arow*1024 + ko*8;
            const bf16* hA = hAb + (size_t)arow*1024 + ko*8;
            bf16 (*Bl)[12288] = (bf16(*)[12288])smem;
            #pragma unroll
            for (int p = 0; p < 6; p++) gload16(spg[p], &Bl[0][(p*256 + tid)*8]);
            bf16x8 aH0 = HS ? *(const bf16x8*)(hA)      : ld_sys128(hA);
            bf16x8 aH1 = HS ? *(const bf16x8*)(hA + 32) : ld_sys128(hA + 32);
            bf16x8 aD0 = *(const bf16x8*)(dA);
            bf16x8 aD1 = *(const bf16x8*)(dA + 32);
            __syncthreads();
            f32x4 acc[6][2] = {};
            for (int kt = 0; kt < 16; ++kt){
                int cur = kt & 1;
                if (kt < 15){
                    int k1 = (kt+1)*64;
                    #pragma unroll
                    for (int p = 0; p < 6; p++)
                        gload16(spg[p] + k1, &Bl[cur ^ 1][(p*256 + tid)*8]);
                }
                bf16x8 nH0 = aH0, nH1 = aH1, nD0 = aD0, nD1 = aD1;
                if (kt < 15){
                    int k1 = (kt+1)*64;
                    nH0 = HS ? *(const bf16x8*)(hA + k1)      : ld_sys128(hA + k1);
                    nH1 = HS ? *(const bf16x8*)(hA + k1 + 32) : ld_sys128(hA + k1 + 32);
                    nD0 = *(const bf16x8*)(dA + k1);
                    nD1 = *(const bf16x8*)(dA + k1 + 32);
                }
                const bf16* Br = &Bl[cur][0];
                #pragma unroll
                for (int g = 0; g < 6; g++){
                    #pragma unroll
                    for (int cfl = 0; cfl < 2; cfl++){
                        bf16x8 b0 = *(const bf16x8*)(&Br[(((g*4 + cfl*2 + 0)*64) + l)*8]);
                        acc[g][cfl] = __builtin_amdgcn_mfma_f32_16x16x32_bf16(
                            g < 3 ? aH0 : aD0, b0, acc[g][cfl], 0,0,0);
                        bf16x8 b1 = *(const bf16x8*)(&Br[(((g*4 + cfl*2 + 1)*64) + l)*8]);
                        acc[g][cfl] = __builtin_amdgcn_mfma_f32_16x16x32_bf16(
                            g < 3 ? aH1 : aD1, b1, acc[g][cfl], 0,0,0);
                    }
                }
                __syncthreads();
                aH0 = nH0; aH1 = nH1; aD0 = nD0; aD1 = nD1;
            }
            bf16 (*rp)[32] = (bf16(*)[32])smem;       // 4KB repack tile
            #pragma unroll
            for (int cfl = 0; cfl < 2; cfl++){
                int j = j0 + cfl*16 + lr;
                float bir = a.bih[j],      bhr = a.bhh[j];
                float biz = a.bih[1024+j], bhz = a.bhh[1024+j];
                float bin = a.bih[2048+j], bhn = a.bhh[2048+j];
                #pragma unroll
                for (int r = 0; r < 4; r++){
                    int m = m0g + w*16 + ko*4 + r;
                    float ir  = acc[0][cfl][r] + bir;
                    float iz  = acc[1][cfl][r] + biz;
                    float in_ = acc[2][cfl][r] + bin;
                    float hr  = acc[3][cfl][r] + bhr;
                    float hz  = acc[4][cfl][r] + bhz;
                    float hn  = acc[5][cfl][r] + bhn;
                    float rg = sigmoidf_(ir + hr);
                    float zg = sigmoidf_(iz + hz);
                    float ng = tanhf(in_ + rg*hn);
                    float dp = dprev_f[(size_t)m*D_ + j];
                    float dn = (1.f - zg)*ng + zg*dp;
                    dout_t[(size_t)m*(T_*D_) + j] = dn;
                    dcur_f[(size_t)m*D_ + j] = dn;
                    rp[w*16 + ko*4 + r][cfl*16 + lr] = (bf16)dn;
                }
            }
            __syncthreads();
            {   // contiguous 16B/thread write-through stores to the t-slab
                int row = tid >> 2, c8 = (tid & 3)*8;
                const u64* q = (const u64*)&rp[row][c8];
                bf16* gp = dall_t + (size_t)(m0g + row)*1024 + j0 + c8;
                st_sys64(gp,     q[0]);
                st_sys64(gp + 4, q[1]);
            }
        }
        gridbar(a.bar, sync_id++);
        // ================= phase 2: po1 (BK=128, 8 iters) =================
        {
            const bf16* Apo = (t == 0) ? a.dall0 : a.partial + (size_t)(t-1)*SLAB_;
            bf16 (*Bl2)[4096] = (bf16(*)[4096])smem;     // 2 x 8KB
            const bf16* A = Apo + (size_t)arow*1024 + ko*8;
            #pragma unroll
            for (int p = 0; p < 2; p++) gload16(spp[p], &Bl2[0][(p*256 + tid)*8]);
            bf16x8 a0 = *(const bf16x8*)(A);
            bf16x8 a1 = *(const bf16x8*)(A + 32);
            bf16x8 a2 = *(const bf16x8*)(A + 64);
            bf16x8 a3 = *(const bf16x8*)(A + 96);
            __syncthreads();
            f32x4 acc[2] = {};
            for (int kt = 0; kt < 8; ++kt){
                int cur = kt & 1;
                if (kt < 7){
                    int k1 = (kt+1)*128;
                    #pragma unroll
                    for (int p = 0; p < 2; p++)
                        gload16(spp[p] + k1, &Bl2[cur ^ 1][(p*256 + tid)*8]);
                }
                bf16x8 n0 = a0, n1 = a1, n2 = a2, n3 = a3;
                if (kt < 7){
                    int k1 = (kt+1)*128;
                    n0 = *(const bf16x8*)(A + k1);
                    n1 = *(const bf16x8*)(A + k1 + 32);
                    n2 = *(const bf16x8*)(A + k1 + 64);
                    n3 = *(const bf16x8*)(A + k1 + 96);
                }
                const bf16* Br = &Bl2[cur][0];
                #pragma unroll
                for (int cfl = 0; cfl < 2; cfl++){
                    bf16x8 b0 = *(const bf16x8*)(&Br[((0*2 + cfl)*64 + l)*8]);
                    acc[cfl] = __builtin_amdgcn_mfma_f32_16x16x32_bf16(a0, b0, acc[cfl], 0,0,0);
                    bf16x8 b1 = *(const bf16x8*)(&Br[((1*2 + cfl)*64 + l)*8]);
                    acc[cfl] = __builtin_amdgcn_mfma_f32_16x16x32_bf16(a1, b1, acc[cfl], 0,0,0);
                    bf16x8 b2 = *(const bf16x8*)(&Br[((2*2 + cfl)*64 + l)*8]);
                    acc[cfl] = __builtin_amdgcn_mfma_f32_16x16x32_bf16(a2, b2, acc[cfl], 0,0,0);
                    bf16x8 b3 = *(const bf16x8*)(&Br[((3*2 + cfl)*64 + l)*8]);
                    acc[cfl] = __builtin_amdgcn_mfma_f32_16x16x32_bf16(a3, b3, acc[cfl], 0,0,0);
                }
                __syncthreads();
                a0 = n0; a1 = n1; a2 = n2; a3 = n3;
            }
            // stage embed-partial tile via SYSLOAD (keeps slab t uncached in L2)
            bf16 (*rp)[32] = (bf16(*)[32])(smem + 16384);  // 4KB
            bf16* emb = (bf16*)(smem + 20480);             // 4KB [64][32]
            {
                int row = tid >> 2, colb = (tid & 3)*8;
                *(bf16x8*)&emb[row*32 + colb] =
                    ld_sys128(a.partial + ((size_t)t*B_ + m0g + row)*1024 + j0 + colb);
            }
            __syncthreads();
            #pragma unroll
            for (int cfl = 0; cfl < 2; cfl++){
                int col = j0 + cfl*16 + lr;
                float bb = a.pob1[col];
                #pragma unroll
                for (int r = 0; r < 4; r++){
                    int lrow = w*16 + ko*4 + r;
                    float v = acc[cfl][r] + bb + (float)emb[lrow*32 + cfl*16 + lr];
                    rp[lrow][cfl*16 + lr] = (bf16)eluf(v);
                }
            }
            __syncthreads();
            {
                int row = tid >> 2, c8 = (tid & 3)*8;
                const u64* q = (const u64*)&rp[row][c8];
                bf16* gp = a.po1h + (size_t)(m0g + row)*1024 + j0 + c8;
                st_sys64(gp,     q[0]);
                st_sys64(gp + 4, q[1]);
            }
        }
        gridbar(a.bar, sync_id++);
        // ================= phase 3: po_out (64 blocks) =================
        if (bid < 64){
            int m0 = bid << 4;
            float (*ps)[16][68] = (float(*)[16][68])smem;           // 17408 B
            bf16 (*smA)[88] = (bf16(*)[88])(smem + 17408);          // 2816 B
            bf16 (*hrep)[2][16][16] = (bf16(*)[2][16][16])(smem + 20224); // 4096 B
            bf16* hd = HS ? (a.hsl + (size_t)(t+1)*SLAB_) : a.h_buf;
            int ks = w * 256;
            f32x4 acc[4] = {};
            const bf16* apo = a.po1h + (size_t)(m0 + lr)*1024 + ks + ko*8;
            bf16x8 av2 = ld_sys128(apo);
            #pragma unroll
            for (int kk = 0; kk < 8; kk++){
                bf16x8 a2n = av2;
                if (kk < 7) a2n = ld_sys128(apo + (kk+1)*32);
                int k = kk*32;
                #pragma unroll
                for (int cf = 0; cf < 4; cf++){
                    bf16x8 b2 = *(const bf16x8*)(a.poW2 + (size_t)(cf*16+lr)*1024 + ks + k + ko*8);
                    acc[cf] = __builtin_amdgcn_mfma_f32_16x16x32_bf16(av2, b2, acc[cf], 0,0,0);
                }
                av2 = a2n;
            }
            #pragma unroll
            for (int cf = 0; cf < 4; cf++){
                int col = cf*16 + lr;
                #pragma unroll
                for (int r = 0; r < 4; r++) ps[w][ko*4+r][col] = acc[cf][r];
            }
            __syncthreads();
            for (int it = 0; it < 2; it++){
                int idx2 = tid + it*256;
                int s = idx2 & 31, mm = idx2 >> 5;
                int mg = m0 + mm;
                float qm  = ps[0][mm][s]    + ps[1][mm][s]    + ps[2][mm][s]    + ps[3][mm][s]    + a.pob2[s];
                float qls = ps[0][mm][32+s] + ps[1][mm][32+s] + ps[2][mm][32+s] + ps[3][mm][32+s] + a.pob2[32+s];
                float qstd = softplusf_(qls) + 0.1f;
                size_t no = (size_t)mg*(T_*S_) + (size_t)t*S_ + s;
                float qst = qm + a.noise_po[no]*qstd;
                a.out[0*(size_t)CH_ + no] = qm;
                a.out[1*(size_t)CH_ + no] = qstd;
                a.out[2*(size_t)CH_ + no] = qst;
                smA[mm][s] = (bf16)qst;
                if (t + 1 < T_)
                    smA[mm][32+s] = (bf16)a.actions[(size_t)mg*(T_*S_) + (size_t)(t+1)*S_ + s];
            }
            __syncthreads();
            if (t + 1 < T_){
                for (int c2 = 0; c2 < 16; c2++){
                    int nb = w*256 + c2*16;
                    int pb = c2 & 1;
                    f32x4 a2v = {0.f, 0.f, 0.f, 0.f};
                    #pragma unroll
                    for (int kk = 0; kk < 2; kk++){
                        bf16x8 avv = *(const bf16x8*)(&smA[lr][kk*32 + ko*8]);
                        bf16x8 bv = *(const bf16x8*)(a.aspW + (size_t)(nb+lr)*64 + kk*32 + ko*8);
                        a2v = __builtin_amdgcn_mfma_f32_16x16x32_bf16(avv, bv, a2v, 0,0,0);
                    }
                    int n2 = nb + lr;
                    float bb = a.aspb[n2];
                    #pragma unroll
                    for (int r = 0; r < 4; r++)
                        hrep[w][pb][ko*4 + r][lr] = (bf16)eluf(a2v[r] + bb);
                    __syncthreads();   // cross-lane LDS handoff needs a barrier
                    u64 q = *(const u64*)&hrep[w][pb][l >> 2][(l & 3)*4];
                    st_sys64(&hd[(size_t)(m0 + (l >> 2))*1024 + nb + (l & 3)*4], q);
                }
            }
        }
        gridbar(a.bar, sync_id++);
    }
}

// ---------------- batched prior path (async-staged B, padded rp1s) ---------
// 1024 blocks x 64 rows. rp1 (4 subtiles) -> rp1s -> rp2 -> sample.
__global__ __launch_bounds__(256) void k_prior(
        const bf16* __restrict__ dallP, const bf16* __restrict__ dall0,
        const bf16* __restrict__ rpW1, const float* __restrict__ rpb1,
        const bf16* __restrict__ rpW2, const float* __restrict__ rpb2,
        const float* __restrict__ noise_pr,
        float* __restrict__ out){
    int bid = blockIdx.x;
    int sl = bid >> 4;
    int b0 = (bid & 15)*64;
    int t  = (sl == 63) ? 0 : sl + 1;
    const bf16* Abase = (sl == 63) ? dall0 : dallP + (size_t)sl*SLAB_;
    int tid = threadIdx.x;
    int w = tid >> 6, l = tid & 63;
    int lr = l & 15, ko = l >> 4;
    __shared__ bf16 Bl[2][8192];       // 16KB per buffer
    __shared__ bf16 rp1s[64][264];     // padded (+8)
    const bf16* Ar = Abase + (size_t)(b0 + w*16 + lr)*1024 + ko*8;
    f32x4 acc2[4] = {};
    const bf16* sp[4];
    {   // sp for subtile 0
        #pragma unroll
        for (int p = 0; p < 4; p++){
            int s = p*256 + tid;
            int f = s >> 6, sl2 = s & 63;
            int col = f*16 + (sl2 & 15);
            sp[p] = rpW1 + (size_t)col*1024 + (sl2 >> 4)*8;
        }
    }
    // prologue: stage subtile-0 tile-0
    #pragma unroll
    for (int p = 0; p < 4; p++) gload16(sp[p], &Bl[0][(p*256 + tid)*8]);
    __syncthreads();
    for (int sub = 0; sub < 4; sub++){
        int c0 = sub*256;
        f32x4 acc[16] = {};
        bf16x8 a = *(const bf16x8*)(Ar);
        for (int kt = 0; kt < 32; ++kt){
            int cur = kt & 1;
            if (kt < 31){
                int k1 = (kt+1)*32;
                #pragma unroll
                for (int p = 0; p < 4; p++)
                    gload16(sp[p] + k1, &Bl[cur ^ 1][(p*256 + tid)*8]);
            }
            bf16x8 an = a;
            if (kt < 31) an = *(const bf16x8*)(Ar + (kt+1)*32);
            const bf16* Br = &Bl[cur][0];
            #pragma unroll
            for (int f = 0; f < 16; f++){
                bf16x8 b = *(const bf16x8*)(&Br[((f*64) + l)*8]);
                acc[f] = __builtin_amdgcn_mfma_f32_16x16x32_bf16(a, b, acc[f], 0,0,0);
            }
            __syncthreads();
            a = an;
        }
        // tail: issue next subtile's first tile into Bl[0] (hides under rp2)
        if (sub < 3){
            int c1 = c0 + 256;
            #pragma unroll
            for (int p = 0; p < 4; p++){
                int s = p*256 + tid;
                int f = s >> 6, sl2 = s & 63;
                int col = c1 + f*16 + (sl2 & 15);
                sp[p] = rpW1 + (size_t)col*1024 + (sl2 >> 4)*8;
                gload16(sp[p], &Bl[0][(p*256 + tid)*8]);
            }
        }
        // rp1 epilogue -> rp1s (padded)
        #pragma unroll
        for (int f = 0; f < 16; f++){
            int col = f*16 + lr;
            float bb = rpb1[c0 + col];
            #pragma unroll
            for (int r = 0; r < 4; r++)
                rp1s[w*16 + ko*4 + r][col] = (bf16)eluf(acc[f][r] + bb);
        }
        __syncthreads();
        // rp2 partial GEMM over this 256-col K-slice
        #pragma unroll
        for (int kk = 0; kk < 8; kk++){
            int k = kk*32;
            bf16x8 a2 = *(const bf16x8*)(&rp1s[w*16 + lr][k + ko*8]);
            #pragma unroll
            for (int cf = 0; cf < 4; cf++){
                bf16x8 b2 = *(const bf16x8*)(rpW2 + (size_t)(cf*16+lr)*1024 + c0 + k + ko*8);
                acc2[cf] = __builtin_amdgcn_mfma_f32_16x16x32_bf16(a2, b2, acc2[cf], 0,0,0);
            }
        }
        __syncthreads();   // rp1s reads done + Bl[0] stage drained (vmcnt at barrier)
    }
    #pragma unroll
    for (int cf = 0; cf < 2; cf++){
        int s = cf*16 + lr;
        float b1 = rpb2[s], b2 = rpb2[32+s];
        #pragma unroll
        for (int r = 0; r < 4; r++){
            int row = w*16 + ko*4 + r;
            float pm  = acc2[cf][r]   + b1;
            float pls = acc2[cf+2][r] + b2;
            float pstd = softplusf_(pls) + 0.1f;
            size_t no = (size_t)(b0 + row)*2048 + (size_t)t*32 + s;
            float pst = pm + noise_pr[no]*pstd;
            out[3*(size_t)CH_ + no] = pm;
            out[4*(size_t)CH_ + no] = pstd;
            out[5*(size_t)CH_ + no] = pst;
        }
    }
}

extern "C" void kernel_launch(void* const* d_in, const int* in_sizes, int n_in,
                              void* d_out, int out_size, void* d_ws, size_t ws_size,
                              hipStream_t stream) {
    const float* embeds   = (const float*)d_in[0];
    const float* actions  = (const float*)d_in[1];
    const float* deter0   = (const float*)d_in[2];
    const float* stoch0   = (const float*)d_in[3];
    const float* noise_pr = (const float*)d_in[4];
    const float* noise_po = (const float*)d_in[5];
    const float* asp_W    = (const float*)d_in[6];
    const float* asp_b    = (const float*)d_in[7];
    const float* w_ih     = (const float*)d_in[8];
    const float* w_hh     = (const float*)d_in[9];
    const float* b_ih     = (const float*)d_in[10];
    const float* b_hh     = (const float*)d_in[11];
    const float* rp_W1    = (const float*)d_in[12];
    const float* rp_b1    = (const float*)d_in[13];
    const float* rp_W2    = (const float*)d_in[14];
    const float* rp_b2    = (const float*)d_in[15];
    const float* po_W1    = (const float*)d_in[16];
    const float* po_b1    = (const float*)d_in[17];
    const float* po_W2    = (const float*)d_in[18];
    const float* po_b2    = (const float*)d_in[19];
    float* out = (float*)d_out;

    char* ws = (char*)d_ws;
    const size_t MB = 1024*1024;
    bf16*  h_buf   = (bf16*)(ws + 0*MB);
    bf16*  dbuf0   = (bf16*)(ws + 2*MB);
    bf16*  po1h    = (bf16*)(ws + 6*MB);
    float* dF0     = (float*)(ws + 10*MB);
    float* dF1     = (float*)(ws + 14*MB);
    bf16*  w_ih_b  = (bf16*)(ws + 18*MB);
    bf16*  w_hh_b  = (bf16*)(ws + 24*MB);
    bf16*  rpW1_b  = (bf16*)(ws + 30*MB);
    bf16*  poW1_b  = (bf16*)(ws + 32*MB);
    bf16*  rpW2_b  = (bf16*)(ws + 36*MB);
    bf16*  poW2_b  = (bf16*)(ws + 36*MB + 256*1024);
    bf16*  aspW_b  = (bf16*)(ws + 36*MB + 512*1024);
    unsigned* bar  = (unsigned*)(ws + 37*MB);   // root 16KB + go 96KB
    bf16*  dall0   = (bf16*)(ws + 38*MB);                  // 2MB: deter t=0 slab
    bf16*  partial = (bf16*)(ws + 40*MB);                  // 128MB, [t][b][n] slabs
    bf16*  hsl     = (bf16*)(ws + 168*MB);                 // 128MB, t-indexed h slabs
    bf16*  embf    = (bf16*)(out + DOFF_);                 // scratch in d_out deter region

    bool hs = ws_size >= (size_t)296*MB;

    hipMemsetAsync(bar, 0, 16384 + 192*8*64, stream);

    auto cvt = [&](const float* s, bf16* d, int n){
        k_cvt<<<(n/4 + 255)/256, 256, 0, stream>>>(s, d, n);
    };
    cvt(w_ih,  w_ih_b, 3072*1024);
    cvt(w_hh,  w_hh_b, 3072*1024);
    cvt(rp_W1, rpW1_b, 1024*1024);
    cvt(po_W1, poW1_b, 1024*2048);
    cvt(rp_W2, rpW2_b, 64*1024);
    cvt(po_W2, poW2_b, 64*1024);
    cvt(asp_W, aspW_b, 1024*64);
    cvt(deter0, dbuf0, 1024*1024);
    k_h0<<<1024, 256, 0, stream>>>(stoch0, actions, asp_W, asp_b,
                                   hs ? hsl : h_buf);
    k_cvt_tr<<<B_*T_, 256, 0, stream>>>(embeds, embf);
    k_pre<<<1024, 256, 0, stream>>>(embf, poW1_b, partial);

    SArgs sa;
    sa.h_buf = h_buf;  sa.hsl = hsl;  sa.dbuf0 = dbuf0;
    sa.wih = w_ih_b;   sa.whh = w_hh_b;
    sa.bih = b_ih;     sa.bhh = b_hh;
    sa.deter0 = deter0;
    sa.dF0 = dF0;      sa.dF1 = dF1;
    sa.out = out;
    sa.poW1 = poW1_b;  sa.pob1 = po_b1;
    sa.partial = partial;
    sa.po1h = po1h;
    sa.poW2 = poW2_b;  sa.pob2 = po_b2;
    sa.noise_po = noise_po;
    sa.actions = actions;
    sa.aspW = aspW_b;  sa.aspb = asp_b;
    sa.dall0 = dall0;
    sa.bar = bar;
    if (hs) k_steps<true><<<512, 256, 0, stream>>>(sa);
    else    k_steps<false><<<512, 256, 0, stream>>>(sa);

    k_prior<<<1024, 256, 0, stream>>>(partial, dall0, rpW1_b, rp_b1,
                                      rpW2_b, rp_b2, noise_pr, out);
}